// Round 8
// baseline (493.232 us; speedup 1.0000x reference)
//
#include <hip/hip_runtime.h>
#include <math.h>

#define BSZ 4096

typedef __attribute__((ext_vector_type(8))) short bf16x8;
typedef __attribute__((ext_vector_type(4))) float f32x4;

// ST layout (floats): rowZ@0, rowF@131072, rowW@262144 (each [32 part][4096])
//                     colZ@393216, colE@524288, colW@655360
//                     Tpart@786432 ([4096 waves][4])
#define ST_ROW 0
#define ST_COL 393216
#define ST_T   786432
#define ST_FLOATS 802816

__device__ __forceinline__ unsigned short f2b(float f) {
    unsigned u = __float_as_uint(f);
    u = u + 0x7fffu + ((u >> 16) & 1u);
    return (unsigned short)(u >> 16);
}
__device__ __forceinline__ float b2f(unsigned short s) {
    return __uint_as_float(((unsigned)s) << 16);
}

// ---------------------------------------------------------------------------
// Merged cast: i (8.4M) + all weights (1.29M) -> contiguous bf16 IB|WB.
// ---------------------------------------------------------------------------
__global__ void cast_all(const float* __restrict__ i_in,
                         const float* __restrict__ l1, const float* __restrict__ l2,
                         const float* __restrict__ l3, const float* __restrict__ tl2,
                         const float* __restrict__ isp, const float* __restrict__ ish,
                         const float* __restrict__ tsh, const float* __restrict__ tsp,
                         unsigned short* __restrict__ o) {
    int i = (blockIdx.x * 256 + threadIdx.x) * 4;
    if (i >= 9682944) return;
    const float* src; int off;
    if (i < 8388608)      { src = i_in; off = 0; }
    else if (i < 9437184) { src = l1;  off = 8388608; }
    else if (i < 9568256) { src = l2;  off = 9437184; }
    else if (i < 9601024) { src = l3;  off = 9568256; }
    else if (i < 9617408) { src = tl2; off = 9601024; }
    else if (i < 9633792) { src = isp; off = 9617408; }
    else if (i < 9650176) { src = ish; off = 9633792; }
    else if (i < 9666560) { src = tsh; off = 9650176; }
    else                  { src = tsp; off = 9666560; }
    float4 v = *(const float4*)(src + (i - off));
    ushort4 r;
    r.x = f2b(v.x); r.y = f2b(v.y); r.z = f2b(v.z); r.w = f2b(v.w);
    *(ushort4*)(o + i) = r;
}

// ---------------------------------------------------------------------------
// SIMT GEMM (only for tl1, K=49), bf16 output.
// ---------------------------------------------------------------------------
__global__ void gemm_small(const float* __restrict__ A, const float* __restrict__ W,
                           const float* __restrict__ bias, unsigned short* __restrict__ C,
                           int M, int N, int K, int relu) {
    __shared__ float As[16][65];
    __shared__ float Ws[16][65];
    const int tx = threadIdx.x, ty = threadIdx.y;
    const int tid = ty * 16 + tx;
    const int m0 = blockIdx.y * 64, n0 = blockIdx.x * 64;
    float acc[4][4] = {};
    const int lrow = tid >> 2;
    const int lkb = (tid & 3) * 4;
    for (int k0 = 0; k0 < K; k0 += 16) {
#pragma unroll
        for (int u = 0; u < 4; ++u) {
            int k = k0 + lkb + u;
            As[lkb + u][lrow] = (k < K) ? A[(size_t)(m0 + lrow) * K + k] : 0.0f;
            Ws[lkb + u][lrow] = (k < K) ? W[(size_t)(n0 + lrow) * K + k] : 0.0f;
        }
        __syncthreads();
#pragma unroll
        for (int kk = 0; kk < 16; ++kk) {
            float av[4], bv[4];
#pragma unroll
            for (int i = 0; i < 4; ++i) av[i] = As[kk][ty * 4 + i];
#pragma unroll
            for (int j = 0; j < 4; ++j) bv[j] = Ws[kk][tx * 4 + j];
#pragma unroll
            for (int i = 0; i < 4; ++i)
#pragma unroll
                for (int j = 0; j < 4; ++j) acc[i][j] += av[i] * bv[j];
        }
        __syncthreads();
    }
#pragma unroll
    for (int i = 0; i < 4; ++i)
#pragma unroll
        for (int j = 0; j < 4; ++j) {
            int n = n0 + tx * 4 + j;
            float v = acc[i][j] + bias[n];
            if (relu) v = fmaxf(v, 0.0f);
            C[(size_t)(m0 + ty * 4 + i) * N + n] = f2b(v);
        }
}

// ---------------------------------------------------------------------------
// Shared MFMA tile loop: acc = A-tile @ W-tile^T, 128x128, 4 waves, BK=64.
// ---------------------------------------------------------------------------
__device__ __forceinline__ void mfma_loop(const unsigned short* __restrict__ A,
                                          const unsigned short* __restrict__ W,
                                          int K, int m0, int n0,
                                          short* As, short* Bs, f32x4 (&acc)[4][4]) {
    const int tid = threadIdx.x;
    const int w = tid >> 6, lane = tid & 63, quad = lane >> 4, l15 = lane & 15;
    const int rw = (w >> 1) * 64, cw = (w & 1) * 64;
    for (int k0 = 0; k0 < K; k0 += 64) {
#pragma unroll
        for (int r = 0; r < 4; ++r) {
            int idx = r * 256 + tid;
            int row = idx >> 3, cbp = idx & 7;
            int col = ((cbp ^ (row & 7)) << 3);
            *(bf16x8*)&As[row * 64 + cbp * 8] = *(const bf16x8*)&A[(size_t)(m0 + row) * K + k0 + col];
            *(bf16x8*)&Bs[row * 64 + cbp * 8] = *(const bf16x8*)&W[(size_t)(n0 + row) * K + k0 + col];
        }
        __syncthreads();
#pragma unroll
        for (int kb = 0; kb < 2; ++kb) {
            bf16x8 af[4], bfr[4];
            int cb = kb * 4 + quad;
#pragma unroll
            for (int i = 0; i < 4; ++i) {
                int row = rw + i * 16 + l15;
                af[i] = *(const bf16x8*)&As[row * 64 + ((cb ^ (row & 7)) << 3)];
            }
#pragma unroll
            for (int j = 0; j < 4; ++j) {
                int row = cw + j * 16 + l15;
                bfr[j] = *(const bf16x8*)&Bs[row * 64 + ((cb ^ (row & 7)) << 3)];
            }
#pragma unroll
            for (int i = 0; i < 4; ++i)
#pragma unroll
                for (int j = 0; j < 4; ++j)
                    acc[i][j] = __builtin_amdgcn_mfma_f32_16x16x32_bf16(af[i], bfr[j], acc[i][j], 0, 0, 0);
        }
        __syncthreads();
    }
}

// Plain MFMA GEMM (L1, L2 of the image chain): bf16 out, optional relu.
__global__ __launch_bounds__(256) void mfma_gemm(const unsigned short* __restrict__ A,
                                                 const unsigned short* __restrict__ W,
                                                 const float* __restrict__ bias,
                                                 unsigned short* __restrict__ Cb,
                                                 int N, int K, int relu) {
    __shared__ alignas(16) short As[128 * 64];
    __shared__ alignas(16) short Bs[128 * 64];
    const int tid = threadIdx.x;
    const int w = tid >> 6, lane = tid & 63, quad = lane >> 4, l15 = lane & 15;
    const int rw = (w >> 1) * 64, cw = (w & 1) * 64;
    const int m0 = blockIdx.y * 128, n0 = blockIdx.x * 128;
    f32x4 acc[4][4];
#pragma unroll
    for (int i = 0; i < 4; ++i)
#pragma unroll
        for (int j = 0; j < 4; ++j) acc[i][j] = (f32x4){0.f, 0.f, 0.f, 0.f};
    mfma_loop(A, W, K, m0, n0, As, Bs, acc);
#pragma unroll
    for (int j = 0; j < 4; ++j) {
        int n = n0 + cw + j * 16 + l15;
        float bv = bias[n];
#pragma unroll
        for (int i = 0; i < 4; ++i)
#pragma unroll
            for (int r = 0; r < 4; ++r) {
                int m = m0 + rw + i * 16 + quad * 4 + r;
                float v = acc[i][j][r] + bv;
                if (relu) v = fmaxf(v, 0.f);
                Cb[(size_t)m * N + n] = f2b(v);
            }
    }
}

// ---------------------------------------------------------------------------
// Chain tails + FUSED row-normalize. z=0: FI2B@l3 (K=256) -> FIB,FINB;
// z=1: FT1B@tl2 (K=128) -> FTB,FTNB. N=128 (block holds full rows).
// ---------------------------------------------------------------------------
__global__ __launch_bounds__(256) void gemm34n(const unsigned short* __restrict__ FI2B,
                                               const unsigned short* __restrict__ FT1B,
                                               const unsigned short* __restrict__ WB,
                                               const float* __restrict__ l3_b,
                                               const float* __restrict__ tl2_b,
                                               unsigned short* __restrict__ FIB,
                                               unsigned short* __restrict__ FTB,
                                               unsigned short* __restrict__ FINB,
                                               unsigned short* __restrict__ FTNB) {
    __shared__ alignas(16) short As[128 * 64];
    __shared__ alignas(16) short Bs[128 * 64];
    __shared__ float rowss[128];
    const int tid = threadIdx.x;
    if (tid < 128) rowss[tid] = 0.f;
    const int z = blockIdx.z;
    const unsigned short* A = z ? FT1B : FI2B;
    const unsigned short* W = z ? (WB + 1212416) : (WB + 1179648);
    const float* bias = z ? tl2_b : l3_b;
    unsigned short* Cb = z ? FTB : FIB;
    unsigned short* CN = z ? FTNB : FINB;
    const int K = z ? 128 : 256;
    const int w = tid >> 6, lane = tid & 63, quad = lane >> 4, l15 = lane & 15;
    const int rw = (w >> 1) * 64, cw = (w & 1) * 64;
    const int m0 = blockIdx.y * 128;
    f32x4 acc[4][4];
#pragma unroll
    for (int i = 0; i < 4; ++i)
#pragma unroll
        for (int j = 0; j < 4; ++j) acc[i][j] = (f32x4){0.f, 0.f, 0.f, 0.f};
    mfma_loop(A, W, K, m0, 0, As, Bs, acc);
    float bv[4];
#pragma unroll
    for (int j = 0; j < 4; ++j) bv[j] = bias[cw + j * 16 + l15];
#pragma unroll
    for (int i = 0; i < 4; ++i)
#pragma unroll
        for (int r = 0; r < 4; ++r) {
            float ssp = 0.f;
#pragma unroll
            for (int j = 0; j < 4; ++j) {
                float v = acc[i][j][r] + bv[j];
                ssp += v * v;
            }
            atomicAdd(&rowss[rw + i * 16 + quad * 4 + r], ssp);
        }
    __syncthreads();
#pragma unroll
    for (int i = 0; i < 4; ++i)
#pragma unroll
        for (int r = 0; r < 4; ++r) {
            int lrow = rw + i * 16 + quad * 4 + r;
            float inv = 1.f / fmaxf(sqrtf(rowss[lrow]), 1e-12f);
#pragma unroll
            for (int j = 0; j < 4; ++j) {
                int n = cw + j * 16 + l15;
                float v = acc[i][j][r] + bv[j];
                Cb[(size_t)(m0 + lrow) * 128 + n] = f2b(v);
                CN[(size_t)(m0 + lrow) * 128 + n] = f2b(v * inv);
            }
        }
}

// ---------------------------------------------------------------------------
// SS heads + FUSED rownorm (z=1,2) + FUSED scalar head dot.
// z: 0=(FIB,isp,c1,out+1) 1=(FIB,ish,c2,out+1+B, ISHN)
//    2=(FTB,tsh,c3,out+1+3B, TSHN) 3=(FTB,tsp,c4,out+1+2B)
// ---------------------------------------------------------------------------
__global__ __launch_bounds__(256) void heads4f(const unsigned short* __restrict__ FIB,
                                               const unsigned short* __restrict__ FTB,
                                               const unsigned short* __restrict__ WB,
                                               const float* __restrict__ bisp, const float* __restrict__ bish,
                                               const float* __restrict__ btsh, const float* __restrict__ btsp,
                                               const float* __restrict__ c1w, const float* __restrict__ c2w,
                                               const float* __restrict__ c3w, const float* __restrict__ c4w,
                                               const float* __restrict__ c1b, const float* __restrict__ c2b,
                                               const float* __restrict__ c3b, const float* __restrict__ c4b,
                                               float* __restrict__ ISP, float* __restrict__ ISH,
                                               float* __restrict__ TSH, float* __restrict__ TSP,
                                               unsigned short* __restrict__ ISHN,
                                               unsigned short* __restrict__ TSHN,
                                               float* __restrict__ out) {
    __shared__ alignas(16) short As[128 * 64];
    __shared__ alignas(16) short Bs[128 * 64];
    __shared__ float rowss[128];
    __shared__ float rowdot[128];
    const int tid = threadIdx.x;
    if (tid < 128) { rowss[tid] = 0.f; rowdot[tid] = 0.f; }
    const int z = blockIdx.z;
    const unsigned short* A = (z < 2) ? FIB : FTB;
    const unsigned short* W = WB + (z == 0 ? 1228800 : z == 1 ? 1245184 : z == 2 ? 1261568 : 1277952);
    const float* bias = z == 0 ? bisp : z == 1 ? bish : z == 2 ? btsh : btsp;
    const float* hw = z == 0 ? c1w : z == 1 ? c2w : z == 2 ? c3w : c4w;
    const float* hb = z == 0 ? c1b : z == 1 ? c2b : z == 2 ? c3b : c4b;
    float* Cf = z == 0 ? ISP : z == 1 ? ISH : z == 2 ? TSH : TSP;
    unsigned short* CN = z == 1 ? ISHN : z == 2 ? TSHN : nullptr;
    const int outoff = z == 0 ? 0 : z == 1 ? 1 : z == 2 ? 3 : 2;
    const int do_norm = (z == 1 || z == 2);
    const int w = tid >> 6, lane = tid & 63, quad = lane >> 4, l15 = lane & 15;
    const int rw = (w >> 1) * 64, cw = (w & 1) * 64;
    const int m0 = blockIdx.y * 128;
    f32x4 acc[4][4];
#pragma unroll
    for (int i = 0; i < 4; ++i)
#pragma unroll
        for (int j = 0; j < 4; ++j) acc[i][j] = (f32x4){0.f, 0.f, 0.f, 0.f};
    mfma_loop(A, W, 128, m0, 0, As, Bs, acc);
    float bv[4], wv[4];
#pragma unroll
    for (int j = 0; j < 4; ++j) {
        int n = cw + j * 16 + l15;
        bv[j] = bias[n];
        wv[j] = hw[n];
    }
#pragma unroll
    for (int i = 0; i < 4; ++i)
#pragma unroll
        for (int r = 0; r < 4; ++r) {
            float ssp = 0.f, dp = 0.f;
#pragma unroll
            for (int j = 0; j < 4; ++j) {
                float v = acc[i][j][r] + bv[j];
                ssp += v * v;
                dp += v * wv[j];
            }
            int lrow = rw + i * 16 + quad * 4 + r;
            atomicAdd(&rowdot[lrow], dp);
            if (do_norm) atomicAdd(&rowss[lrow], ssp);
        }
    __syncthreads();
#pragma unroll
    for (int i = 0; i < 4; ++i)
#pragma unroll
        for (int r = 0; r < 4; ++r) {
            int lrow = rw + i * 16 + quad * 4 + r;
            float inv = do_norm ? (1.f / fmaxf(sqrtf(rowss[lrow]), 1e-12f)) : 0.f;
#pragma unroll
            for (int j = 0; j < 4; ++j) {
                int n = cw + j * 16 + l15;
                float v = acc[i][j][r] + bv[j];
                Cf[(size_t)(m0 + lrow) * 128 + n] = v;
                if (do_norm) CN[(size_t)(m0 + lrow) * 128 + n] = f2b(v * inv);
            }
        }
    if (tid < 128) out[1 + (size_t)outoff * BSZ + m0 + tid] = rowdot[tid] + hb[0];
}

// ---------------------------------------------------------------------------
// MFMA CLIP tile (z=2 merged): LDS-atomic stat reduction (replaces the
// R5 butterfly: 60 ds_add/thread vs ~240 shfl+add). 32 partials per row/col.
// ---------------------------------------------------------------------------
__global__ __launch_bounds__(256) void clip_mfma(const unsigned short* __restrict__ In1,
                                                 const unsigned short* __restrict__ Tn1,
                                                 const unsigned short* __restrict__ In2,
                                                 const unsigned short* __restrict__ Tn2,
                                                 const int* __restrict__ y,
                                                 const float* __restrict__ scale_log1,
                                                 const float* __restrict__ scale_log2,
                                                 float* __restrict__ st1, float* __restrict__ st2) {
    __shared__ alignas(16) short As[128 * 64];
    __shared__ alignas(16) short Bs[128 * 64];
    __shared__ float SR[3][128];
    __shared__ float SC[3][128];
    const int tid = threadIdx.x;
    if (tid < 128) {
        SR[0][tid] = 0.f; SR[1][tid] = 0.f; SR[2][tid] = 0.f;
        SC[0][tid] = 0.f; SC[1][tid] = 0.f; SC[2][tid] = 0.f;
    }
    const int z = blockIdx.z;
    const unsigned short* In = z ? In2 : In1;
    const unsigned short* Tn = z ? Tn2 : Tn1;
    const float* scale_log = z ? scale_log2 : scale_log1;
    float* st = z ? st2 : st1;
    const int w = tid >> 6, lane = tid & 63, quad = lane >> 4, l15 = lane & 15;
    const int bx = blockIdx.x, by = blockIdx.y;
    const int r0 = by * 128, c0 = bx * 128;
    const int rw = (w >> 1) * 64, cw = (w & 1) * 64;
    f32x4 acc[4][4];
#pragma unroll
    for (int i = 0; i < 4; ++i)
#pragma unroll
        for (int j = 0; j < 4; ++j) acc[i][j] = (f32x4){0.f, 0.f, 0.f, 0.f};
    mfma_loop(In, Tn, 128, r0, c0, As, Bs, acc);

    const float s = expf(scale_log[0]);
    int yrow[4][4]; float mrow[4][4];
    int ycol[4];    float mcol[4];
#pragma unroll
    for (int i = 0; i < 4; ++i)
#pragma unroll
        for (int r = 0; r < 4; ++r) {
            int yy = y[r0 + rw + i * 16 + quad * 4 + r];
            yrow[i][r] = yy; mrow[i][r] = (yy == 0) ? 1.f : 0.f;
        }
#pragma unroll
    for (int j = 0; j < 4; ++j) {
        int yy = y[c0 + cw + j * 16 + l15];
        ycol[j] = yy; mcol[j] = (yy == 0) ? 1.f : 0.f;
    }
    float rZ[4][4] = {}, rF[4][4] = {}, rW[4][4] = {};
    float cZ[4] = {}, cE[4] = {}, cW[4] = {};
    float aAll = 0.f, aC0 = 0.f, aR0 = 0.f, aRC = 0.f;
#pragma unroll
    for (int i = 0; i < 4; ++i)
#pragma unroll
        for (int r = 0; r < 4; ++r) {
            float mr = mrow[i][r];
            int yr = yrow[i][r];
#pragma unroll
            for (int j = 0; j < 4; ++j) {
                float S = acc[i][j][r];
                float L = s * S;
                float e1 = __expf(L);
                float e2 = __expf(S);
                float msk = (yr == ycol[j]) ? 1.f : 0.f;
                rZ[i][r] += e1; rF[i][r] += e1 * L; rW[i][r] += e1 * msk;
                cZ[j] += e2;    cE[j] += e2 * S;    cW[j] += e2 * msk;
                float tmp = S * mcol[j];
                aAll += S; aC0 += tmp; aR0 += S * mr; aRC += tmp * mr;
            }
        }
    // LDS-atomic accumulation (row: 32 lanes/addr; col: conflict-free per wave)
#pragma unroll
    for (int i = 0; i < 4; ++i)
#pragma unroll
        for (int r = 0; r < 4; ++r) {
            int lrow = rw + i * 16 + quad * 4 + r;
            atomicAdd(&SR[0][lrow], rZ[i][r]);
            atomicAdd(&SR[1][lrow], rF[i][r]);
            atomicAdd(&SR[2][lrow], rW[i][r]);
        }
#pragma unroll
    for (int j = 0; j < 4; ++j) {
        int lcol = cw + j * 16 + l15;
        atomicAdd(&SC[0][lcol], cZ[j]);
        atomicAdd(&SC[1][lcol], cE[j]);
        atomicAdd(&SC[2][lcol], cW[j]);
    }
    // T scalars: per-wave butterfly + store (unchanged)
#pragma unroll
    for (int m = 1; m < 64; m <<= 1) {
        aAll += __shfl_xor(aAll, m); aC0 += __shfl_xor(aC0, m);
        aR0 += __shfl_xor(aR0, m);   aRC += __shfl_xor(aRC, m);
    }
    if (lane == 0) {
        int wg = (by * 32 + bx) * 4 + w;
        float T00 = aRC, T01 = aR0 - aRC, T10 = aC0 - aRC, T11 = aAll - aR0 - aC0 + aRC;
        st[ST_T + wg * 4 + 0] = T00;
        st[ST_T + wg * 4 + 1] = T01;
        st[ST_T + wg * 4 + 2] = T10;
        st[ST_T + wg * 4 + 3] = T11;
    }
    __syncthreads();
    if (tid < 128) {
        int base = ST_ROW + bx * 4096 + r0 + tid;
        st[base]          = SR[0][tid];
        st[base + 131072] = SR[1][tid];
        st[base + 262144] = SR[2][tid];
    } else {
        int t2 = tid - 128;
        int base = ST_COL + by * 4096 + c0 + t2;
        st[base]          = SC[0][t2];
        st[base + 131072] = SC[1][t2];
        st[base + 262144] = SC[2][t2];
    }
}

// ---------------------------------------------------------------------------
// CLIP finalize: 32 partials per row -> half-wave per row (32 lanes).
// grid (512, 2), block 256 = 8 rows. Block (0,z) reduces T-partials -> TT.
// ---------------------------------------------------------------------------
__global__ __launch_bounds__(256) void clip_finalize(const float* __restrict__ st1,
                                                     const float* __restrict__ st2,
                                                     const int* __restrict__ y,
                                                     float* __restrict__ RV,
                                                     float* __restrict__ TT) {
    __shared__ float cred[256];
    const int z = blockIdx.y;
    const float* st = z ? st2 : st1;
    const int tid = threadIdx.x;
    const int lane32 = tid & 31;
    const int k = blockIdx.x * 8 + (tid >> 5);
    const float Bf = (float)BSZ;

    float ccnt = 0.f;
    for (int i = tid; i < BSZ; i += 256) ccnt += (y[i] == 0) ? 1.f : 0.f;
    cred[tid] = ccnt;
    __syncthreads();
    for (int ss2 = 128; ss2 > 0; ss2 >>= 1) {
        if (tid < ss2) cred[tid] += cred[tid + ss2];
        __syncthreads();
    }
    const float n0 = cred[0];

    const int base = lane32 * 4096 + k;
    float Z1 = st[ST_ROW + base];
    float F1 = st[ST_ROW + 131072 + base];
    float W1 = st[ST_ROW + 262144 + base];
    float Z2 = st[ST_COL + base];
    float E2 = st[ST_COL + 131072 + base];
    float W2 = st[ST_COL + 262144 + base];
#pragma unroll
    for (int m = 1; m < 32; m <<= 1) {
        Z1 += __shfl_xor(Z1, m); F1 += __shfl_xor(F1, m); W1 += __shfl_xor(W1, m);
        Z2 += __shfl_xor(Z2, m); E2 += __shfl_xor(E2, m); W2 += __shfl_xor(W2, m);
    }
    if (lane32 == 0) {
        int yk = y[k];
        float n = (yk == 0) ? n0 : (Bf - n0);
        float a = 1.0f / n;
        float ea = expf(a);
        float denom = n * ea + (Bf - n);
        float q_s = ea / denom, q_d = 1.0f / denom;
        float ld = logf(denom);
        float lq_s = a - ld, lq_d = -ld;
        float Qlq = n * q_s * lq_s + (Bf - n) * q_d * lq_d;
        float term_r = Qlq + F1 / Z1 - lq_d - (lq_s - lq_d) * (W1 / Z1);
        float term_c = Qlq + E2 / Z2 - lq_d - (lq_s - lq_d) * (W2 / Z2);
        RV[(size_t)z * BSZ + k] = (term_r + term_c) / (4.0f * Bf);
    }
    if (blockIdx.x == 0) {
        __shared__ float4 tred[256];
        const float4* tp = (const float4*)&st[ST_T];
        float4 acc = {0.f, 0.f, 0.f, 0.f};
        for (int u = tid; u < 4096; u += 256) {
            float4 t4 = tp[u];
            acc.x += t4.x; acc.y += t4.y; acc.z += t4.z; acc.w += t4.w;
        }
        tred[tid] = acc;
        __syncthreads();
        for (int ss2 = 128; ss2 > 0; ss2 >>= 1) {
            if (tid < ss2) {
                tred[tid].x += tred[tid + ss2].x; tred[tid].y += tred[tid + ss2].y;
                tred[tid].z += tred[tid + ss2].z; tred[tid].w += tred[tid + ss2].w;
            }
            __syncthreads();
        }
        if (tid == 0) {
            TT[z * 4 + 0] = tred[0].x; TT[z * 4 + 1] = tred[0].y;
            TT[z * 4 + 2] = tred[0].z; TT[z * 4 + 3] = tred[0].w;
        }
    }
}

// ---------------------------------------------------------------------------
// gram_splitk: G_mat = X^T X (128x128, K=4096) split-K in 64-row chunks, fp32.
// ---------------------------------------------------------------------------
__global__ __launch_bounds__(256) void gram_splitk(const float* __restrict__ isp,
                                                   const float* __restrict__ ish,
                                                   const float* __restrict__ tsp,
                                                   const float* __restrict__ tsh,
                                                   float* __restrict__ GP) {
    __shared__ alignas(16) float As2[64][128];
    const int mat = blockIdx.y, chunk = blockIdx.x;
    const float* A = mat == 0 ? isp : mat == 1 ? ish : mat == 2 ? tsp : tsh;
    const int tid = threadIdx.x;
    const int m0 = chunk * 64;
#pragma unroll
    for (int r = 0; r < 8; ++r) {
        int idx = r * 256 + tid;
        int row = idx >> 5, c4 = (idx & 31) * 4;
        *(float4*)&As2[row][c4] = *(const float4*)&A[(size_t)(m0 + row) * 128 + c4];
    }
    __syncthreads();
    const int ty = tid >> 4, tx = tid & 15;
    float acc[8][8] = {};
    for (int k = 0; k < 64; ++k) {
        float av[8], bv[8];
        *(float4*)&av[0] = *(const float4*)&As2[k][ty * 8];
        *(float4*)&av[4] = *(const float4*)&As2[k][ty * 8 + 4];
        *(float4*)&bv[0] = *(const float4*)&As2[k][tx * 8];
        *(float4*)&bv[4] = *(const float4*)&As2[k][tx * 8 + 4];
#pragma unroll
        for (int i = 0; i < 8; ++i)
#pragma unroll
            for (int j = 0; j < 8; ++j) acc[i][j] += av[i] * bv[j];
    }
    float* Gp = GP + ((size_t)(mat * 64 + chunk) << 14);
#pragma unroll
    for (int i = 0; i < 8; ++i) {
        *(float4*)&Gp[(ty * 8 + i) * 128 + tx * 8]     = *(float4*)&acc[i][0];
        *(float4*)&Gp[(ty * 8 + i) * 128 + tx * 8 + 4] = *(float4*)&acc[i][4];
    }
}

// frob_combine: grid (64,2), block 64 (1 wave). Each block: 256 entries.
__global__ void frob_combine(const float* __restrict__ GP, float* __restrict__ scal) {
    const int z = blockIdx.y;
    const int tid = threadIdx.x;
    int u = blockIdx.x * 256 + tid * 4;
    float4 ga = {0.f, 0.f, 0.f, 0.f};
    float4 gb = {0.f, 0.f, 0.f, 0.f};
    const size_t baseA = ((size_t)(2 * z) * 64) << 14;
    const size_t baseB = ((size_t)(2 * z + 1) * 64) << 14;
    for (int c = 0; c < 64; ++c) {
        float4 va = *(const float4*)&GP[baseA + ((size_t)c << 14) + u];
        float4 vb = *(const float4*)&GP[baseB + ((size_t)c << 14) + u];
        ga.x += va.x; ga.y += va.y; ga.z += va.z; ga.w += va.w;
        gb.x += vb.x; gb.y += vb.y; gb.z += vb.z; gb.w += vb.w;
    }
    float r = ga.x * gb.x + ga.y * gb.y + ga.z * gb.z + ga.w * gb.w;
#pragma unroll
    for (int m = 1; m < 64; m <<= 1) r += __shfl_xor(r, m);
    if (tid == 0) atomicAdd(&scal[3 + z], r);
}

// ---------------------------------------------------------------------------
// Final: sum RV per z (+ recount n0) + T tails + gram terms -> out[0]
// ---------------------------------------------------------------------------
__global__ void final_kernel(const float* __restrict__ RV, const float* __restrict__ scal,
                             const int* __restrict__ y,
                             const float* __restrict__ sl1, const float* __restrict__ sl2,
                             float* __restrict__ out) {
    __shared__ float red0[256], red1[256], red2[256];
    int tid = threadIdx.x;
    float s0 = 0.f, s1 = 0.f, cnt = 0.f;
    for (int u = tid; u < BSZ; u += 256) {
        s0 += RV[u]; s1 += RV[BSZ + u];
        cnt += (y[u] == 0) ? 1.f : 0.f;
    }
    red0[tid] = s0; red1[tid] = s1; red2[tid] = cnt;
    __syncthreads();
    for (int ss = 128; ss > 0; ss >>= 1) {
        if (tid < ss) {
            red0[tid] += red0[tid + ss]; red1[tid] += red1[tid + ss];
            red2[tid] += red2[tid + ss];
        }
        __syncthreads();
    }
    if (tid == 0) {
        const float Bf = (float)BSZ;
        float n0 = red2[0], n1 = Bf - n0;
        float e0 = expf(1.f / n0), e1 = expf(1.f / n1);
        float d0 = n0 * e0 + (Bf - n0), d1 = n1 * e1 + (Bf - n1);
        float qs0 = e0 / d0, qd0 = 1.f / d0, qs1 = e1 / d1, qd1 = 1.f / d1;
        float loss_z[2];
        for (int z = 0; z < 2; ++z) {
            float T00 = scal[8 + z * 4 + 0], T01 = scal[8 + z * 4 + 1];
            float T10 = scal[8 + z * 4 + 2], T11 = scal[8 + z * 4 + 3];
            float QS1 = qd0 * (T00 + T01) + (qs0 - qd0) * T00 + qd1 * (T10 + T11) + (qs1 - qd1) * T11;
            float QS2 = qd0 * (T00 + T10) + (qs0 - qd0) * T00 + qd1 * (T01 + T11) + (qs1 - qd1) * T11;
            float s = expf(z ? sl2[0] : sl1[0]);
            loss_z[z] = (z ? red1[0] : red0[0]) + (-s * QS1 - QS2) / (4.0f * Bf);
        }
        float loss_sp = 0.5f * (sqrtf(scal[4]) + sqrtf(scal[3]));
        out[0] = (loss_sp + loss_z[1] + loss_z[0]) / 3.0f;
    }
}

// ---------------------------------------------------------------------------
extern "C" void kernel_launch(void* const* d_in, const int* in_sizes, int n_in,
                              void* d_out, int out_size, void* d_ws, size_t ws_size,
                              hipStream_t stream) {
    const float* i_in  = (const float*)d_in[0];
    const float* t_in  = (const float*)d_in[1];
    const int*   y     = (const int*)d_in[2];
    const float* l1_w  = (const float*)d_in[3];
    const float* l1_b  = (const float*)d_in[4];
    const float* l2_w  = (const float*)d_in[5];
    const float* l2_b  = (const float*)d_in[6];
    const float* l3_w  = (const float*)d_in[7];
    const float* l3_b  = (const float*)d_in[8];
    const float* tl1_w = (const float*)d_in[9];
    const float* tl1_b = (const float*)d_in[10];
    const float* tl2_w = (const float*)d_in[11];
    const float* tl2_b = (const float*)d_in[12];
    const float* isp_w = (const float*)d_in[13];
    const float* isp_b = (const float*)d_in[14];
    const float* ish_w = (const float*)d_in[15];
    const float* ish_b = (const float*)d_in[16];
    const float* tsh_w = (const float*)d_in[17];
    const float* tsh_b = (const float*)d_in[18];
    const float* tsp_w = (const float*)d_in[19];
    const float* tsp_b = (const float*)d_in[20];
    const float* c1_w  = (const float*)d_in[21];
    const float* c1_b  = (const float*)d_in[22];
    const float* c2_w  = (const float*)d_in[23];
    const float* c2_b  = (const float*)d_in[24];
    const float* c3_w  = (const float*)d_in[25];
    const float* c3_b  = (const float*)d_in[26];
    const float* c4_w  = (const float*)d_in[27];
    const float* c4_b  = (const float*)d_in[28];
    const float* scale1 = (const float*)d_in[29];
    const float* scale2 = (const float*)d_in[30];

    float* ws = (float*)d_ws;
    float* SCAL = ws;                       // 64 (zeroed; [3],[4] frob; [8..15] T)
    float* RV   = ws + 64;                  // 2*4096
    float* ISP  = RV + 2 * BSZ;
    float* ISH  = ISP + (size_t)BSZ * 128;
    float* TSP  = ISH + (size_t)BSZ * 128;
    float* TSH  = TSP + (size_t)BSZ * 128;
    unsigned short* IB   = (unsigned short*)(TSH + (size_t)BSZ * 128);
    unsigned short* WB   = IB + (size_t)BSZ * 2048;      // 1294336
    unsigned short* FI1B = WB + 1294336;
    unsigned short* FI2B = FI1B + (size_t)BSZ * 512;
    unsigned short* FIB  = FI2B + (size_t)BSZ * 256;
    unsigned short* FT1B = FIB + (size_t)BSZ * 128;
    unsigned short* FTB  = FT1B + (size_t)BSZ * 128;
    unsigned short* FINB = FTB + (size_t)BSZ * 128;
    unsigned short* FTNB = FINB + (size_t)BSZ * 128;
    unsigned short* ISHN = FTNB + (size_t)BSZ * 128;
    unsigned short* TSHN = ISHN + (size_t)BSZ * 128;
    // ST (2 x 802816 floats) and GP (4.19M floats) alias IB (stream-ordered).
    float* ST1 = (float*)IB;
    float* ST2 = ST1 + ST_FLOATS;
    float* GP = (float*)IB;

    float* out = (float*)d_out;

    hipMemsetAsync(d_ws, 0, 64 * sizeof(float), stream);
    cast_all<<<9456, 256, 0, stream>>>(i_in, l1_w, l2_w, l3_w, tl2_w, isp_w, ish_w, tsh_w, tsp_w, IB);
    gemm_small<<<dim3(2, 64), dim3(16, 16), 0, stream>>>(t_in, tl1_w, tl1_b, FT1B, BSZ, 128, 49, 1);

    mfma_gemm<<<dim3(4, 32), 256, 0, stream>>>(IB, WB, l1_b, FI1B, 512, 2048, 1);
    mfma_gemm<<<dim3(2, 32), 256, 0, stream>>>(FI1B, WB + 1048576, l2_b, FI2B, 256, 512, 1);
    gemm34n<<<dim3(1, 32, 2), 256, 0, stream>>>(FI2B, FT1B, WB, l3_b, tl2_b, FIB, FTB, FINB, FTNB);
    heads4f<<<dim3(1, 32, 4), 256, 0, stream>>>(FIB, FTB, WB, isp_b, ish_b, tsh_b, tsp_b,
                                                c1_w, c2_w, c3_w, c4_w, c1_b, c2_b, c3_b, c4_b,
                                                ISP, ISH, TSH, TSP, ISHN, TSHN, out);

    clip_mfma<<<dim3(32, 32, 2), 256, 0, stream>>>(FINB, FTNB, ISHN, TSHN, y, scale1, scale2, ST1, ST2);
    clip_finalize<<<dim3(512, 2), 256, 0, stream>>>(ST1, ST2, y, RV, &SCAL[8]);

    gram_splitk<<<dim3(64, 4), 256, 0, stream>>>(ISP, ISH, TSP, TSH, GP);
    frob_combine<<<dim3(64, 2), 64, 0, stream>>>(GP, SCAL);
    final_kernel<<<1, 256, 0, stream>>>(RV, SCAL, y, scale1, scale2, out);
}

// Round 9
// 332.899 us; speedup vs baseline: 1.4816x; 1.4816x over previous
//
#include <hip/hip_runtime.h>
#include <math.h>

#define BSZ 4096

typedef __attribute__((ext_vector_type(8))) short bf16x8;
typedef __attribute__((ext_vector_type(4))) float f32x4;

// ST layout (floats): rowZ@0, rowF@262144, rowW@524288 (each [64 part][4096 row])
//                     colZ@786432, colE@1048576, colW@1310720
//                     Tpart@1572864 ([4096 waves][4])
#define ST_ROW 0
#define ST_COL 786432
#define ST_T   1572864
#define ST_FLOATS 1589248

__device__ __forceinline__ unsigned short f2b(float f) {
    unsigned u = __float_as_uint(f);
    u = u + 0x7fffu + ((u >> 16) & 1u);
    return (unsigned short)(u >> 16);
}
__device__ __forceinline__ float b2f(unsigned short s) {
    return __uint_as_float(((unsigned)s) << 16);
}

// ---------------------------------------------------------------------------
// Merged cast: i (8.4M) + all weights (1.29M) -> contiguous bf16 IB|WB.
// ---------------------------------------------------------------------------
__global__ void cast_all(const float* __restrict__ i_in,
                         const float* __restrict__ l1, const float* __restrict__ l2,
                         const float* __restrict__ l3, const float* __restrict__ tl2,
                         const float* __restrict__ isp, const float* __restrict__ ish,
                         const float* __restrict__ tsh, const float* __restrict__ tsp,
                         unsigned short* __restrict__ o) {
    int i = (blockIdx.x * 256 + threadIdx.x) * 4;
    if (i >= 9682944) return;
    const float* src; int off;
    if (i < 8388608)      { src = i_in; off = 0; }
    else if (i < 9437184) { src = l1;  off = 8388608; }
    else if (i < 9568256) { src = l2;  off = 9437184; }
    else if (i < 9601024) { src = l3;  off = 9568256; }
    else if (i < 9617408) { src = tl2; off = 9601024; }
    else if (i < 9633792) { src = isp; off = 9617408; }
    else if (i < 9650176) { src = ish; off = 9633792; }
    else if (i < 9666560) { src = tsh; off = 9650176; }
    else                  { src = tsp; off = 9666560; }
    float4 v = *(const float4*)(src + (i - off));
    ushort4 r;
    r.x = f2b(v.x); r.y = f2b(v.y); r.z = f2b(v.z); r.w = f2b(v.w);
    *(ushort4*)(o + i) = r;
}

// ---------------------------------------------------------------------------
// SIMT GEMM (only for tl1, K=49), bf16 output.
// ---------------------------------------------------------------------------
__global__ void gemm_small(const float* __restrict__ A, const float* __restrict__ W,
                           const float* __restrict__ bias, unsigned short* __restrict__ C,
                           int M, int N, int K, int relu) {
    __shared__ float As[16][65];
    __shared__ float Ws[16][65];
    const int tx = threadIdx.x, ty = threadIdx.y;
    const int tid = ty * 16 + tx;
    const int m0 = blockIdx.y * 64, n0 = blockIdx.x * 64;
    float acc[4][4] = {};
    const int lrow = tid >> 2;
    const int lkb = (tid & 3) * 4;
    for (int k0 = 0; k0 < K; k0 += 16) {
#pragma unroll
        for (int u = 0; u < 4; ++u) {
            int k = k0 + lkb + u;
            As[lkb + u][lrow] = (k < K) ? A[(size_t)(m0 + lrow) * K + k] : 0.0f;
            Ws[lkb + u][lrow] = (k < K) ? W[(size_t)(n0 + lrow) * K + k] : 0.0f;
        }
        __syncthreads();
#pragma unroll
        for (int kk = 0; kk < 16; ++kk) {
            float av[4], bv[4];
#pragma unroll
            for (int i = 0; i < 4; ++i) av[i] = As[kk][ty * 4 + i];
#pragma unroll
            for (int j = 0; j < 4; ++j) bv[j] = Ws[kk][tx * 4 + j];
#pragma unroll
            for (int i = 0; i < 4; ++i)
#pragma unroll
                for (int j = 0; j < 4; ++j) acc[i][j] += av[i] * bv[j];
        }
        __syncthreads();
    }
#pragma unroll
    for (int i = 0; i < 4; ++i)
#pragma unroll
        for (int j = 0; j < 4; ++j) {
            int n = n0 + tx * 4 + j;
            float v = acc[i][j] + bias[n];
            if (relu) v = fmaxf(v, 0.0f);
            C[(size_t)(m0 + ty * 4 + i) * N + n] = f2b(v);
        }
}

// ---------------------------------------------------------------------------
// Shared MFMA tile loop: acc = A-tile @ W-tile^T, 128x128, 4 waves, BK=64.
// ---------------------------------------------------------------------------
__device__ __forceinline__ void mfma_loop(const unsigned short* __restrict__ A,
                                          const unsigned short* __restrict__ W,
                                          int K, int m0, int n0,
                                          short* As, short* Bs, f32x4 (&acc)[4][4]) {
    const int tid = threadIdx.x;
    const int w = tid >> 6, lane = tid & 63, quad = lane >> 4, l15 = lane & 15;
    const int rw = (w >> 1) * 64, cw = (w & 1) * 64;
    for (int k0 = 0; k0 < K; k0 += 64) {
#pragma unroll
        for (int r = 0; r < 4; ++r) {
            int idx = r * 256 + tid;
            int row = idx >> 3, cbp = idx & 7;
            int col = ((cbp ^ (row & 7)) << 3);
            *(bf16x8*)&As[row * 64 + cbp * 8] = *(const bf16x8*)&A[(size_t)(m0 + row) * K + k0 + col];
            *(bf16x8*)&Bs[row * 64 + cbp * 8] = *(const bf16x8*)&W[(size_t)(n0 + row) * K + k0 + col];
        }
        __syncthreads();
#pragma unroll
        for (int kb = 0; kb < 2; ++kb) {
            bf16x8 af[4], bfr[4];
            int cb = kb * 4 + quad;
#pragma unroll
            for (int i = 0; i < 4; ++i) {
                int row = rw + i * 16 + l15;
                af[i] = *(const bf16x8*)&As[row * 64 + ((cb ^ (row & 7)) << 3)];
            }
#pragma unroll
            for (int j = 0; j < 4; ++j) {
                int row = cw + j * 16 + l15;
                bfr[j] = *(const bf16x8*)&Bs[row * 64 + ((cb ^ (row & 7)) << 3)];
            }
#pragma unroll
            for (int i = 0; i < 4; ++i)
#pragma unroll
                for (int j = 0; j < 4; ++j)
                    acc[i][j] = __builtin_amdgcn_mfma_f32_16x16x32_bf16(af[i], bfr[j], acc[i][j], 0, 0, 0);
        }
        __syncthreads();
    }
}

// Plain MFMA GEMM (L1, L2 of the image chain): bf16 out, optional relu.
__global__ __launch_bounds__(256) void mfma_gemm(const unsigned short* __restrict__ A,
                                                 const unsigned short* __restrict__ W,
                                                 const float* __restrict__ bias,
                                                 unsigned short* __restrict__ Cb,
                                                 int N, int K, int relu) {
    __shared__ alignas(16) short As[128 * 64];
    __shared__ alignas(16) short Bs[128 * 64];
    const int tid = threadIdx.x;
    const int w = tid >> 6, lane = tid & 63, quad = lane >> 4, l15 = lane & 15;
    const int rw = (w >> 1) * 64, cw = (w & 1) * 64;
    const int m0 = blockIdx.y * 128, n0 = blockIdx.x * 128;
    f32x4 acc[4][4];
#pragma unroll
    for (int i = 0; i < 4; ++i)
#pragma unroll
        for (int j = 0; j < 4; ++j) acc[i][j] = (f32x4){0.f, 0.f, 0.f, 0.f};
    mfma_loop(A, W, K, m0, n0, As, Bs, acc);
#pragma unroll
    for (int j = 0; j < 4; ++j) {
        int n = n0 + cw + j * 16 + l15;
        float bv = bias[n];
#pragma unroll
        for (int i = 0; i < 4; ++i)
#pragma unroll
            for (int r = 0; r < 4; ++r) {
                int m = m0 + rw + i * 16 + quad * 4 + r;
                float v = acc[i][j][r] + bv;
                if (relu) v = fmaxf(v, 0.f);
                Cb[(size_t)m * N + n] = f2b(v);
            }
    }
}

// ---------------------------------------------------------------------------
// Chain tails + FUSED row-normalize. z=0: FI2B@l3 (K=256) -> FIB,FINB;
// z=1: FT1B@tl2 (K=128) -> FTB,FTNB. N=128 (block holds full rows).
// rowss LDS atomics here are fine: only 4 waves x 1 add per (lrow) pair.
// ---------------------------------------------------------------------------
__global__ __launch_bounds__(256) void gemm34n(const unsigned short* __restrict__ FI2B,
                                               const unsigned short* __restrict__ FT1B,
                                               const unsigned short* __restrict__ WB,
                                               const float* __restrict__ l3_b,
                                               const float* __restrict__ tl2_b,
                                               unsigned short* __restrict__ FIB,
                                               unsigned short* __restrict__ FTB,
                                               unsigned short* __restrict__ FINB,
                                               unsigned short* __restrict__ FTNB) {
    __shared__ alignas(16) short As[128 * 64];
    __shared__ alignas(16) short Bs[128 * 64];
    __shared__ float rowss[128];
    const int tid = threadIdx.x;
    if (tid < 128) rowss[tid] = 0.f;
    const int z = blockIdx.z;
    const unsigned short* A = z ? FT1B : FI2B;
    const unsigned short* W = z ? (WB + 1212416) : (WB + 1179648);
    const float* bias = z ? tl2_b : l3_b;
    unsigned short* Cb = z ? FTB : FIB;
    unsigned short* CN = z ? FTNB : FINB;
    const int K = z ? 128 : 256;
    const int w = tid >> 6, lane = tid & 63, quad = lane >> 4, l15 = lane & 15;
    const int rw = (w >> 1) * 64, cw = (w & 1) * 64;
    const int m0 = blockIdx.y * 128;
    f32x4 acc[4][4];
#pragma unroll
    for (int i = 0; i < 4; ++i)
#pragma unroll
        for (int j = 0; j < 4; ++j) acc[i][j] = (f32x4){0.f, 0.f, 0.f, 0.f};
    mfma_loop(A, W, K, m0, 0, As, Bs, acc);
    float bv[4];
#pragma unroll
    for (int j = 0; j < 4; ++j) bv[j] = bias[cw + j * 16 + l15];
#pragma unroll
    for (int i = 0; i < 4; ++i)
#pragma unroll
        for (int r = 0; r < 4; ++r) {
            float ssp = 0.f;
#pragma unroll
            for (int j = 0; j < 4; ++j) {
                float v = acc[i][j][r] + bv[j];
                ssp += v * v;
            }
            // pre-reduce across the 16 lanes of the quad before touching LDS
#pragma unroll
            for (int m = 1; m < 16; m <<= 1) ssp += __shfl_xor(ssp, m);
            if (l15 == 0) atomicAdd(&rowss[rw + i * 16 + quad * 4 + r], ssp);
        }
    __syncthreads();
#pragma unroll
    for (int i = 0; i < 4; ++i)
#pragma unroll
        for (int r = 0; r < 4; ++r) {
            int lrow = rw + i * 16 + quad * 4 + r;
            float inv = 1.f / fmaxf(sqrtf(rowss[lrow]), 1e-12f);
#pragma unroll
            for (int j = 0; j < 4; ++j) {
                int n = cw + j * 16 + l15;
                float v = acc[i][j][r] + bv[j];
                Cb[(size_t)(m0 + lrow) * 128 + n] = f2b(v);
                CN[(size_t)(m0 + lrow) * 128 + n] = f2b(v * inv);
            }
        }
}

// ---------------------------------------------------------------------------
// SS heads + FUSED rownorm (z=1,2) + FUSED scalar head dot.
// ---------------------------------------------------------------------------
__global__ __launch_bounds__(256) void heads4f(const unsigned short* __restrict__ FIB,
                                               const unsigned short* __restrict__ FTB,
                                               const unsigned short* __restrict__ WB,
                                               const float* __restrict__ bisp, const float* __restrict__ bish,
                                               const float* __restrict__ btsh, const float* __restrict__ btsp,
                                               const float* __restrict__ c1w, const float* __restrict__ c2w,
                                               const float* __restrict__ c3w, const float* __restrict__ c4w,
                                               const float* __restrict__ c1b, const float* __restrict__ c2b,
                                               const float* __restrict__ c3b, const float* __restrict__ c4b,
                                               float* __restrict__ ISP, float* __restrict__ ISH,
                                               float* __restrict__ TSH, float* __restrict__ TSP,
                                               unsigned short* __restrict__ ISHN,
                                               unsigned short* __restrict__ TSHN,
                                               float* __restrict__ out) {
    __shared__ alignas(16) short As[128 * 64];
    __shared__ alignas(16) short Bs[128 * 64];
    __shared__ float rowss[128];
    __shared__ float rowdot[128];
    const int tid = threadIdx.x;
    if (tid < 128) { rowss[tid] = 0.f; rowdot[tid] = 0.f; }
    const int z = blockIdx.z;
    const unsigned short* A = (z < 2) ? FIB : FTB;
    const unsigned short* W = WB + (z == 0 ? 1228800 : z == 1 ? 1245184 : z == 2 ? 1261568 : 1277952);
    const float* bias = z == 0 ? bisp : z == 1 ? bish : z == 2 ? btsh : btsp;
    const float* hw = z == 0 ? c1w : z == 1 ? c2w : z == 2 ? c3w : c4w;
    const float* hb = z == 0 ? c1b : z == 1 ? c2b : z == 2 ? c3b : c4b;
    float* Cf = z == 0 ? ISP : z == 1 ? ISH : z == 2 ? TSH : TSP;
    unsigned short* CN = z == 1 ? ISHN : z == 2 ? TSHN : nullptr;
    const int outoff = z == 0 ? 0 : z == 1 ? 1 : z == 2 ? 3 : 2;
    const int do_norm = (z == 1 || z == 2);
    const int w = tid >> 6, lane = tid & 63, quad = lane >> 4, l15 = lane & 15;
    const int rw = (w >> 1) * 64, cw = (w & 1) * 64;
    const int m0 = blockIdx.y * 128;
    f32x4 acc[4][4];
#pragma unroll
    for (int i = 0; i < 4; ++i)
#pragma unroll
        for (int j = 0; j < 4; ++j) acc[i][j] = (f32x4){0.f, 0.f, 0.f, 0.f};
    mfma_loop(A, W, 128, m0, 0, As, Bs, acc);
    float bv[4], wv[4];
#pragma unroll
    for (int j = 0; j < 4; ++j) {
        int n = cw + j * 16 + l15;
        bv[j] = bias[n];
        wv[j] = hw[n];
    }
#pragma unroll
    for (int i = 0; i < 4; ++i)
#pragma unroll
        for (int r = 0; r < 4; ++r) {
            float ssp = 0.f, dp = 0.f;
#pragma unroll
            for (int j = 0; j < 4; ++j) {
                float v = acc[i][j][r] + bv[j];
                ssp += v * v;
                dp += v * wv[j];
            }
#pragma unroll
            for (int m = 1; m < 16; m <<= 1) {
                ssp += __shfl_xor(ssp, m);
                dp += __shfl_xor(dp, m);
            }
            if (l15 == 0) {
                int lrow = rw + i * 16 + quad * 4 + r;
                atomicAdd(&rowdot[lrow], dp);
                if (do_norm) atomicAdd(&rowss[lrow], ssp);
            }
        }
    __syncthreads();
#pragma unroll
    for (int i = 0; i < 4; ++i)
#pragma unroll
        for (int r = 0; r < 4; ++r) {
            int lrow = rw + i * 16 + quad * 4 + r;
            float inv = do_norm ? (1.f / fmaxf(sqrtf(rowss[lrow]), 1e-12f)) : 0.f;
#pragma unroll
            for (int j = 0; j < 4; ++j) {
                int n = cw + j * 16 + l15;
                float v = acc[i][j][r] + bv[j];
                Cf[(size_t)(m0 + lrow) * 128 + n] = v;
                if (do_norm) CN[(size_t)(m0 + lrow) * 128 + n] = f2b(v * inv);
            }
        }
    if (tid < 128) out[1 + (size_t)outoff * BSZ + m0 + tid] = rowdot[tid] + hb[0];
}

// ---------------------------------------------------------------------------
// MFMA CLIP tile (z=2 merged): R7-proven version. BK=64 staging (32 KB LDS),
// R5 butterfly epilogue (VGPR 124, 51 us measured). DO NOT: transpose-reduce
// (R6: VGPR 168, 4x slower) or LDS same-address atomics (R8: serialization,
// 4x slower). The butterfly keeps only 3 stats live at a time.
// ---------------------------------------------------------------------------
__global__ __launch_bounds__(256) void clip_mfma(const unsigned short* __restrict__ In1,
                                                 const unsigned short* __restrict__ Tn1,
                                                 const unsigned short* __restrict__ In2,
                                                 const unsigned short* __restrict__ Tn2,
                                                 const int* __restrict__ y,
                                                 const float* __restrict__ scale_log1,
                                                 const float* __restrict__ scale_log2,
                                                 float* __restrict__ st1, float* __restrict__ st2) {
    __shared__ alignas(16) short As[128 * 64];
    __shared__ alignas(16) short Bs[128 * 64];
    const int z = blockIdx.z;
    const unsigned short* In = z ? In2 : In1;
    const unsigned short* Tn = z ? Tn2 : Tn1;
    const float* scale_log = z ? scale_log2 : scale_log1;
    float* st = z ? st2 : st1;
    const int tid = threadIdx.x;
    const int w = tid >> 6, lane = tid & 63, quad = lane >> 4, l15 = lane & 15;
    const int bx = blockIdx.x, by = blockIdx.y;
    const int r0 = by * 128, c0 = bx * 128;
    const int rw = (w >> 1) * 64, cw = (w & 1) * 64;
    f32x4 acc[4][4];
#pragma unroll
    for (int i = 0; i < 4; ++i)
#pragma unroll
        for (int j = 0; j < 4; ++j) acc[i][j] = (f32x4){0.f, 0.f, 0.f, 0.f};
    mfma_loop(In, Tn, 128, r0, c0, As, Bs, acc);

    const float s = expf(scale_log[0]);
    int yrow[4][4]; float mrow[4][4];
    int ycol[4];    float mcol[4];
#pragma unroll
    for (int i = 0; i < 4; ++i)
#pragma unroll
        for (int r = 0; r < 4; ++r) {
            int yy = y[r0 + rw + i * 16 + quad * 4 + r];
            yrow[i][r] = yy; mrow[i][r] = (yy == 0) ? 1.f : 0.f;
        }
#pragma unroll
    for (int j = 0; j < 4; ++j) {
        int yy = y[c0 + cw + j * 16 + l15];
        ycol[j] = yy; mcol[j] = (yy == 0) ? 1.f : 0.f;
    }
    float rZ[4][4] = {}, rF[4][4] = {}, rW[4][4] = {};
    float cZ[4] = {}, cE[4] = {}, cW[4] = {};
    float aAll = 0.f, aC0 = 0.f, aR0 = 0.f, aRC = 0.f;
#pragma unroll
    for (int i = 0; i < 4; ++i)
#pragma unroll
        for (int r = 0; r < 4; ++r) {
            float mr = mrow[i][r];
            int yr = yrow[i][r];
#pragma unroll
            for (int j = 0; j < 4; ++j) {
                float S = acc[i][j][r];
                float L = s * S;
                float e1 = __expf(L);
                float e2 = __expf(S);
                float msk = (yr == ycol[j]) ? 1.f : 0.f;
                rZ[i][r] += e1; rF[i][r] += e1 * L; rW[i][r] += e1 * msk;
                cZ[j] += e2;    cE[j] += e2 * S;    cW[j] += e2 * msk;
                float tmp = S * mcol[j];
                aAll += S; aC0 += tmp; aR0 += S * mr; aRC += tmp * mr;
            }
        }
    // row partials: butterfly over the 16 lanes of each quad; guarded store
    const int p_row = bx * 2 + (cw >> 6);
#pragma unroll
    for (int i = 0; i < 4; ++i)
#pragma unroll
        for (int r = 0; r < 4; ++r) {
#pragma unroll
            for (int m = 1; m < 16; m <<= 1) {
                rZ[i][r] += __shfl_xor(rZ[i][r], m);
                rF[i][r] += __shfl_xor(rF[i][r], m);
                rW[i][r] += __shfl_xor(rW[i][r], m);
            }
            if (l15 == (i * 4 + r)) {
                int grow = r0 + rw + i * 16 + quad * 4 + r;
                int base = ST_ROW + p_row * 4096 + grow;
                st[base]          = rZ[i][r];
                st[base + 262144] = rF[i][r];
                st[base + 524288] = rW[i][r];
            }
        }
    // col partials: reduce across quads
    const int p_col = by * 2 + (rw >> 6);
#pragma unroll
    for (int j = 0; j < 4; ++j) {
        cZ[j] += __shfl_xor(cZ[j], 16); cZ[j] += __shfl_xor(cZ[j], 32);
        cE[j] += __shfl_xor(cE[j], 16); cE[j] += __shfl_xor(cE[j], 32);
        cW[j] += __shfl_xor(cW[j], 16); cW[j] += __shfl_xor(cW[j], 32);
        if (quad == 0) {
            int gcol = c0 + cw + j * 16 + l15;
            int base = ST_COL + p_col * 4096 + gcol;
            st[base]          = cZ[j];
            st[base + 262144] = cE[j];
            st[base + 524288] = cW[j];
        }
    }
    // T scalars: per-wave reduce + store
#pragma unroll
    for (int m = 1; m < 64; m <<= 1) {
        aAll += __shfl_xor(aAll, m); aC0 += __shfl_xor(aC0, m);
        aR0 += __shfl_xor(aR0, m);   aRC += __shfl_xor(aRC, m);
    }
    if (lane == 0) {
        int wg = (by * 32 + bx) * 4 + w;
        float T00 = aRC, T01 = aR0 - aRC, T10 = aC0 - aRC, T11 = aAll - aR0 - aC0 + aRC;
        st[ST_T + wg * 4 + 0] = T00;
        st[ST_T + wg * 4 + 1] = T01;
        st[ST_T + wg * 4 + 2] = T10;
        st[ST_T + wg * 4 + 3] = T11;
    }
}

// ---------------------------------------------------------------------------
// CLIP finalize (R7-proven): one WAVE per row (lane = partial index).
// grid (1024, 2), block 256 = 4 rows. county folded in; block (0,z) -> TT.
// ---------------------------------------------------------------------------
__global__ __launch_bounds__(256) void clip_finalize(const float* __restrict__ st1,
                                                     const float* __restrict__ st2,
                                                     const int* __restrict__ y,
                                                     float* __restrict__ RV,
                                                     float* __restrict__ TT) {
    __shared__ float cred[256];
    const int z = blockIdx.y;
    const float* st = z ? st2 : st1;
    const int tid = threadIdx.x;
    const int lane = tid & 63;
    const int k = blockIdx.x * 4 + (tid >> 6);
    const float Bf = (float)BSZ;

    float ccnt = 0.f;
    for (int i = tid; i < BSZ; i += 256) ccnt += (y[i] == 0) ? 1.f : 0.f;
    cred[tid] = ccnt;
    __syncthreads();
    for (int ss2 = 128; ss2 > 0; ss2 >>= 1) {
        if (tid < ss2) cred[tid] += cred[tid + ss2];
        __syncthreads();
    }
    const float n0 = cred[0];

    const int base = lane * 4096 + k;
    float Z1 = st[ST_ROW + base];
    float F1 = st[ST_ROW + 262144 + base];
    float W1 = st[ST_ROW + 524288 + base];
    float Z2 = st[ST_COL + base];
    float E2 = st[ST_COL + 262144 + base];
    float W2 = st[ST_COL + 524288 + base];
#pragma unroll
    for (int m = 1; m < 64; m <<= 1) {
        Z1 += __shfl_xor(Z1, m); F1 += __shfl_xor(F1, m); W1 += __shfl_xor(W1, m);
        Z2 += __shfl_xor(Z2, m); E2 += __shfl_xor(E2, m); W2 += __shfl_xor(W2, m);
    }
    if (lane == 0) {
        int yk = y[k];
        float n = (yk == 0) ? n0 : (Bf - n0);
        float a = 1.0f / n;
        float ea = expf(a);
        float denom = n * ea + (Bf - n);
        float q_s = ea / denom, q_d = 1.0f / denom;
        float ld = logf(denom);
        float lq_s = a - ld, lq_d = -ld;
        float Qlq = n * q_s * lq_s + (Bf - n) * q_d * lq_d;
        float term_r = Qlq + F1 / Z1 - lq_d - (lq_s - lq_d) * (W1 / Z1);
        float term_c = Qlq + E2 / Z2 - lq_d - (lq_s - lq_d) * (W2 / Z2);
        RV[(size_t)z * BSZ + k] = (term_r + term_c) / (4.0f * Bf);
    }
    if (blockIdx.x == 0) {
        __shared__ float4 tred[256];
        const float4* tp = (const float4*)&st[ST_T];
        float4 acc = {0.f, 0.f, 0.f, 0.f};
        for (int u = tid; u < 4096; u += 256) {
            float4 t4 = tp[u];
            acc.x += t4.x; acc.y += t4.y; acc.z += t4.z; acc.w += t4.w;
        }
        tred[tid] = acc;
        __syncthreads();
        for (int ss2 = 128; ss2 > 0; ss2 >>= 1) {
            if (tid < ss2) {
                tred[tid].x += tred[tid + ss2].x; tred[tid].y += tred[tid + ss2].y;
                tred[tid].z += tred[tid + ss2].z; tred[tid].w += tred[tid + ss2].w;
            }
            __syncthreads();
        }
        if (tid == 0) {
            TT[z * 4 + 0] = tred[0].x; TT[z * 4 + 1] = tred[0].y;
            TT[z * 4 + 2] = tred[0].z; TT[z * 4 + 3] = tred[0].w;
        }
    }
}

// ---------------------------------------------------------------------------
// gram_splitk: G_mat = X^T X (128x128, K=4096) split-K in 64-row chunks, fp32.
// ---------------------------------------------------------------------------
__global__ __launch_bounds__(256) void gram_splitk(const float* __restrict__ isp,
                                                   const float* __restrict__ ish,
                                                   const float* __restrict__ tsp,
                                                   const float* __restrict__ tsh,
                                                   float* __restrict__ GP) {
    __shared__ alignas(16) float As2[64][128];
    const int mat = blockIdx.y, chunk = blockIdx.x;
    const float* A = mat == 0 ? isp : mat == 1 ? ish : mat == 2 ? tsp : tsh;
    const int tid = threadIdx.x;
    const int m0 = chunk * 64;
#pragma unroll
    for (int r = 0; r < 8; ++r) {
        int idx = r * 256 + tid;
        int row = idx >> 5, c4 = (idx & 31) * 4;
        *(float4*)&As2[row][c4] = *(const float4*)&A[(size_t)(m0 + row) * 128 + c4];
    }
    __syncthreads();
    const int ty = tid >> 4, tx = tid & 15;
    float acc[8][8] = {};
    for (int k = 0; k < 64; ++k) {
        float av[8], bv[8];
        *(float4*)&av[0] = *(const float4*)&As2[k][ty * 8];
        *(float4*)&av[4] = *(const float4*)&As2[k][ty * 8 + 4];
        *(float4*)&bv[0] = *(const float4*)&As2[k][tx * 8];
        *(float4*)&bv[4] = *(const float4*)&As2[k][tx * 8 + 4];
#pragma unroll
        for (int i = 0; i < 8; ++i)
#pragma unroll
            for (int j = 0; j < 8; ++j) acc[i][j] += av[i] * bv[j];
    }
    float* Gp = GP + ((size_t)(mat * 64 + chunk) << 14);
#pragma unroll
    for (int i = 0; i < 8; ++i) {
        *(float4*)&Gp[(ty * 8 + i) * 128 + tx * 8]     = *(float4*)&acc[i][0];
        *(float4*)&Gp[(ty * 8 + i) * 128 + tx * 8 + 4] = *(float4*)&acc[i][4];
    }
}

// frob_combine: grid (64,2), block 64 (1 wave). Each block: 256 entries.
__global__ void frob_combine(const float* __restrict__ GP, float* __restrict__ scal) {
    const int z = blockIdx.y;
    const int tid = threadIdx.x;
    int u = blockIdx.x * 256 + tid * 4;
    float4 ga = {0.f, 0.f, 0.f, 0.f};
    float4 gb = {0.f, 0.f, 0.f, 0.f};
    const size_t baseA = ((size_t)(2 * z) * 64) << 14;
    const size_t baseB = ((size_t)(2 * z + 1) * 64) << 14;
    for (int c = 0; c < 64; ++c) {
        float4 va = *(const float4*)&GP[baseA + ((size_t)c << 14) + u];
        float4 vb = *(const float4*)&GP[baseB + ((size_t)c << 14) + u];
        ga.x += va.x; ga.y += va.y; ga.z += va.z; ga.w += va.w;
        gb.x += vb.x; gb.y += vb.y; gb.z += vb.z; gb.w += vb.w;
    }
    float r = ga.x * gb.x + ga.y * gb.y + ga.z * gb.z + ga.w * gb.w;
#pragma unroll
    for (int m = 1; m < 64; m <<= 1) r += __shfl_xor(r, m);
    if (tid == 0) atomicAdd(&scal[3 + z], r);
}

// ---------------------------------------------------------------------------
// Final: sum RV per z (+ recount n0) + T tails + gram terms -> out[0]
// ---------------------------------------------------------------------------
__global__ void final_kernel(const float* __restrict__ RV, const float* __restrict__ scal,
                             const int* __restrict__ y,
                             const float* __restrict__ sl1, const float* __restrict__ sl2,
                             float* __restrict__ out) {
    __shared__ float red0[256], red1[256], red2[256];
    int tid = threadIdx.x;
    float s0 = 0.f, s1 = 0.f, cnt = 0.f;
    for (int u = tid; u < BSZ; u += 256) {
        s0 += RV[u]; s1 += RV[BSZ + u];
        cnt += (y[u] == 0) ? 1.f : 0.f;
    }
    red0[tid] = s0; red1[tid] = s1; red2[tid] = cnt;
    __syncthreads();
    for (int ss = 128; ss > 0; ss >>= 1) {
        if (tid < ss) {
            red0[tid] += red0[tid + ss]; red1[tid] += red1[tid + ss];
            red2[tid] += red2[tid + ss];
        }
        __syncthreads();
    }
    if (tid == 0) {
        const float Bf = (float)BSZ;
        float n0 = red2[0], n1 = Bf - n0;
        float e0 = expf(1.f / n0), e1 = expf(1.f / n1);
        float d0 = n0 * e0 + (Bf - n0), d1 = n1 * e1 + (Bf - n1);
        float qs0 = e0 / d0, qd0 = 1.f / d0, qs1 = e1 / d1, qd1 = 1.f / d1;
        float loss_z[2];
        for (int z = 0; z < 2; ++z) {
            float T00 = scal[8 + z * 4 + 0], T01 = scal[8 + z * 4 + 1];
            float T10 = scal[8 + z * 4 + 2], T11 = scal[8 + z * 4 + 3];
            float QS1 = qd0 * (T00 + T01) + (qs0 - qd0) * T00 + qd1 * (T10 + T11) + (qs1 - qd1) * T11;
            float QS2 = qd0 * (T00 + T10) + (qs0 - qd0) * T00 + qd1 * (T01 + T11) + (qs1 - qd1) * T11;
            float s = expf(z ? sl2[0] : sl1[0]);
            loss_z[z] = (z ? red1[0] : red0[0]) + (-s * QS1 - QS2) / (4.0f * Bf);
        }
        float loss_sp = 0.5f * (sqrtf(scal[4]) + sqrtf(scal[3]));
        out[0] = (loss_sp + loss_z[1] + loss_z[0]) / 3.0f;
    }
}

// ---------------------------------------------------------------------------
extern "C" void kernel_launch(void* const* d_in, const int* in_sizes, int n_in,
                              void* d_out, int out_size, void* d_ws, size_t ws_size,
                              hipStream_t stream) {
    const float* i_in  = (const float*)d_in[0];
    const float* t_in  = (const float*)d_in[1];
    const int*   y     = (const int*)d_in[2];
    const float* l1_w  = (const float*)d_in[3];
    const float* l1_b  = (const float*)d_in[4];
    const float* l2_w  = (const float*)d_in[5];
    const float* l2_b  = (const float*)d_in[6];
    const float* l3_w  = (const float*)d_in[7];
    const float* l3_b  = (const float*)d_in[8];
    const float* tl1_w = (const float*)d_in[9];
    const float* tl1_b = (const float*)d_in[10];
    const float* tl2_w = (const float*)d_in[11];
    const float* tl2_b = (const float*)d_in[12];
    const float* isp_w = (const float*)d_in[13];
    const float* isp_b = (const float*)d_in[14];
    const float* ish_w = (const float*)d_in[15];
    const float* ish_b = (const float*)d_in[16];
    const float* tsh_w = (const float*)d_in[17];
    const float* tsh_b = (const float*)d_in[18];
    const float* tsp_w = (const float*)d_in[19];
    const float* tsp_b = (const float*)d_in[20];
    const float* c1_w  = (const float*)d_in[21];
    const float* c1_b  = (const float*)d_in[22];
    const float* c2_w  = (const float*)d_in[23];
    const float* c2_b  = (const float*)d_in[24];
    const float* c3_w  = (const float*)d_in[25];
    const float* c3_b  = (const float*)d_in[26];
    const float* c4_w  = (const float*)d_in[27];
    const float* c4_b  = (const float*)d_in[28];
    const float* scale1 = (const float*)d_in[29];
    const float* scale2 = (const float*)d_in[30];

    float* ws = (float*)d_ws;
    float* SCAL = ws;                       // 64 (zeroed; [3],[4] frob; [8..15] T)
    float* RV   = ws + 64;                  // 2*4096
    float* ISP  = RV + 2 * BSZ;
    float* ISH  = ISP + (size_t)BSZ * 128;
    float* TSP  = ISH + (size_t)BSZ * 128;
    float* TSH  = TSP + (size_t)BSZ * 128;
    unsigned short* IB   = (unsigned short*)(TSH + (size_t)BSZ * 128);
    unsigned short* WB   = IB + (size_t)BSZ * 2048;      // 1294336
    unsigned short* FI1B = WB + 1294336;
    unsigned short* FI2B = FI1B + (size_t)BSZ * 512;
    unsigned short* FIB  = FI2B + (size_t)BSZ * 256;
    unsigned short* FT1B = FIB + (size_t)BSZ * 128;
    unsigned short* FTB  = FT1B + (size_t)BSZ * 128;
    unsigned short* FINB = FTB + (size_t)BSZ * 128;
    unsigned short* FTNB = FINB + (size_t)BSZ * 128;
    unsigned short* ISHN = FTNB + (size_t)BSZ * 128;
    unsigned short* TSHN = ISHN + (size_t)BSZ * 128;
    // ST (2 x 1589248 floats = 12.7 MB) and GP (16.8 MB) alias IB (16.8 MB),
    // stream-ordered: IB consumed by L1 gemm; ST consumed by clip_finalize.
    float* ST1 = (float*)IB;
    float* ST2 = ST1 + ST_FLOATS;
    float* GP = (float*)IB;

    float* out = (float*)d_out;

    hipMemsetAsync(d_ws, 0, 64 * sizeof(float), stream);
    cast_all<<<9456, 256, 0, stream>>>(i_in, l1_w, l2_w, l3_w, tl2_w, isp_w, ish_w, tsh_w, tsp_w, IB);
    gemm_small<<<dim3(2, 64), dim3(16, 16), 0, stream>>>(t_in, tl1_w, tl1_b, FT1B, BSZ, 128, 49, 1);

    mfma_gemm<<<dim3(4, 32), 256, 0, stream>>>(IB, WB, l1_b, FI1B, 512, 2048, 1);
    mfma_gemm<<<dim3(2, 32), 256, 0, stream>>>(FI1B, WB + 1048576, l2_b, FI2B, 256, 512, 1);
    gemm34n<<<dim3(1, 32, 2), 256, 0, stream>>>(FI2B, FT1B, WB, l3_b, tl2_b, FIB, FTB, FINB, FTNB);
    heads4f<<<dim3(1, 32, 4), 256, 0, stream>>>(FIB, FTB, WB, isp_b, ish_b, tsh_b, tsp_b,
                                                c1_w, c2_w, c3_w, c4_w, c1_b, c2_b, c3_b, c4_b,
                                                ISP, ISH, TSH, TSP, ISHN, TSHN, out);

    clip_mfma<<<dim3(32, 32, 2), 256, 0, stream>>>(FINB, FTNB, ISHN, TSHN, y, scale1, scale2, ST1, ST2);
    clip_finalize<<<dim3(1024, 2), 256, 0, stream>>>(ST1, ST2, y, RV, &SCAL[8]);

    gram_splitk<<<dim3(64, 4), 256, 0, stream>>>(ISP, ISH, TSP, TSH, GP);
    frob_combine<<<dim3(64, 2), 64, 0, stream>>>(GP, SCAL);
    final_kernel<<<1, 256, 0, stream>>>(RV, SCAL, y, scale1, scale2, out);
}

// Round 10
// 306.940 us; speedup vs baseline: 1.6069x; 1.0846x over previous
//
#include <hip/hip_runtime.h>
#include <math.h>

#define BSZ 4096

typedef __attribute__((ext_vector_type(8))) short bf16x8;
typedef __attribute__((ext_vector_type(4))) float f32x4;

// ST layout (floats), TRANSPOSED for coalesced finalize loads:
//   rowZ@0, rowF@262144, rowW@524288   each [4096 row][64 part]
//   colZ@786432, colE@1048576, colW@1310720  each [4096 col][64 part]
//   Tpart@1572864 ([4096 waves][4])
#define ST_ROW 0
#define ST_COL 786432
#define ST_T   1572864
#define ST_FLOATS 1589248

__device__ __forceinline__ unsigned short f2b(float f) {
    unsigned u = __float_as_uint(f);
    u = u + 0x7fffu + ((u >> 16) & 1u);
    return (unsigned short)(u >> 16);
}
__device__ __forceinline__ float b2f(unsigned short s) {
    return __uint_as_float(((unsigned)s) << 16);
}

// ---------------------------------------------------------------------------
// prep: blocks <9456 cast i+weights -> bf16 IB|WB; blocks >=9456 run the
// tl1 SIMT GEMM (K=49, fp32 in, bf16 out). Independent work, one launch.
// ---------------------------------------------------------------------------
__global__ void prep_kernel(const float* __restrict__ i_in,
                            const float* __restrict__ l1, const float* __restrict__ l2,
                            const float* __restrict__ l3, const float* __restrict__ tl2,
                            const float* __restrict__ isp, const float* __restrict__ ish,
                            const float* __restrict__ tsh, const float* __restrict__ tsp,
                            unsigned short* __restrict__ o,
                            const float* __restrict__ t_in, const float* __restrict__ tl1_w,
                            const float* __restrict__ tl1_b, unsigned short* __restrict__ FT1B) {
    __shared__ float As[16][65];
    __shared__ float Ws[16][65];
    if (blockIdx.x < 9456) {
        int i = (blockIdx.x * 256 + threadIdx.x) * 4;
        if (i >= 9682944) return;
        const float* src; int off;
        if (i < 8388608)      { src = i_in; off = 0; }
        else if (i < 9437184) { src = l1;  off = 8388608; }
        else if (i < 9568256) { src = l2;  off = 9437184; }
        else if (i < 9601024) { src = l3;  off = 9568256; }
        else if (i < 9617408) { src = tl2; off = 9601024; }
        else if (i < 9633792) { src = isp; off = 9617408; }
        else if (i < 9650176) { src = ish; off = 9633792; }
        else if (i < 9666560) { src = tsh; off = 9650176; }
        else                  { src = tsp; off = 9666560; }
        float4 v = *(const float4*)(src + (i - off));
        ushort4 r;
        r.x = f2b(v.x); r.y = f2b(v.y); r.z = f2b(v.z); r.w = f2b(v.w);
        *(ushort4*)(o + i) = r;
        return;
    }
    // tl1 gemm: b in [0,128): bx = b&1 (N tiles of 64, N=128), by = b>>1 (64 M tiles)
    const int b = blockIdx.x - 9456;
    const int tid = threadIdx.x;
    const int tx = tid & 15, ty = tid >> 4;
    const int m0 = (b >> 1) * 64, n0 = (b & 1) * 64;
    const int K = 49, N = 128;
    float acc[4][4] = {};
    const int lrow = tid >> 2;
    const int lkb = (tid & 3) * 4;
    for (int k0 = 0; k0 < K; k0 += 16) {
#pragma unroll
        for (int u = 0; u < 4; ++u) {
            int k = k0 + lkb + u;
            As[lkb + u][lrow] = (k < K) ? t_in[(size_t)(m0 + lrow) * K + k] : 0.0f;
            Ws[lkb + u][lrow] = (k < K) ? tl1_w[(size_t)(n0 + lrow) * K + k] : 0.0f;
        }
        __syncthreads();
#pragma unroll
        for (int kk = 0; kk < 16; ++kk) {
            float av[4], bv[4];
#pragma unroll
            for (int i = 0; i < 4; ++i) av[i] = As[kk][ty * 4 + i];
#pragma unroll
            for (int j = 0; j < 4; ++j) bv[j] = Ws[kk][tx * 4 + j];
#pragma unroll
            for (int i = 0; i < 4; ++i)
#pragma unroll
                for (int j = 0; j < 4; ++j) acc[i][j] += av[i] * bv[j];
        }
        __syncthreads();
    }
#pragma unroll
    for (int i = 0; i < 4; ++i)
#pragma unroll
        for (int j = 0; j < 4; ++j) {
            int n = n0 + tx * 4 + j;
            float v = fmaxf(acc[i][j] + tl1_b[n], 0.0f);
            FT1B[(size_t)(m0 + ty * 4 + i) * N + n] = f2b(v);
        }
}

// ---------------------------------------------------------------------------
// Shared MFMA tile loop (128-row tiles): acc = A @ W^T, 4 waves, BK=64.
// ---------------------------------------------------------------------------
__device__ __forceinline__ void mfma_loop(const unsigned short* __restrict__ A,
                                          const unsigned short* __restrict__ W,
                                          int K, int m0, int n0,
                                          short* As, short* Bs, f32x4 (&acc)[4][4]) {
    const int tid = threadIdx.x;
    const int w = tid >> 6, lane = tid & 63, quad = lane >> 4, l15 = lane & 15;
    const int rw = (w >> 1) * 64, cw = (w & 1) * 64;
    for (int k0 = 0; k0 < K; k0 += 64) {
#pragma unroll
        for (int r = 0; r < 4; ++r) {
            int idx = r * 256 + tid;
            int row = idx >> 3, cbp = idx & 7;
            int col = ((cbp ^ (row & 7)) << 3);
            *(bf16x8*)&As[row * 64 + cbp * 8] = *(const bf16x8*)&A[(size_t)(m0 + row) * K + k0 + col];
            *(bf16x8*)&Bs[row * 64 + cbp * 8] = *(const bf16x8*)&W[(size_t)(n0 + row) * K + k0 + col];
        }
        __syncthreads();
#pragma unroll
        for (int kb = 0; kb < 2; ++kb) {
            bf16x8 af[4], bfr[4];
            int cb = kb * 4 + quad;
#pragma unroll
            for (int i = 0; i < 4; ++i) {
                int row = rw + i * 16 + l15;
                af[i] = *(const bf16x8*)&As[row * 64 + ((cb ^ (row & 7)) << 3)];
            }
#pragma unroll
            for (int j = 0; j < 4; ++j) {
                int row = cw + j * 16 + l15;
                bfr[j] = *(const bf16x8*)&Bs[row * 64 + ((cb ^ (row & 7)) << 3)];
            }
#pragma unroll
            for (int i = 0; i < 4; ++i)
#pragma unroll
                for (int j = 0; j < 4; ++j)
                    acc[i][j] = __builtin_amdgcn_mfma_f32_16x16x32_bf16(af[i], bfr[j], acc[i][j], 0, 0, 0);
        }
        __syncthreads();
    }
}

// ---------------------------------------------------------------------------
// 64x128 M-tile MFMA GEMM (L1/L2): doubles grid occupancy vs 128-tile.
// 4 waves each cover 32x64 (acc 2x4). LDS 24 KB.
// ---------------------------------------------------------------------------
__global__ __launch_bounds__(256) void mfma_gemm64(const unsigned short* __restrict__ A,
                                                   const unsigned short* __restrict__ W,
                                                   const float* __restrict__ bias,
                                                   unsigned short* __restrict__ Cb,
                                                   int N, int K, int relu) {
    __shared__ alignas(16) short As[64 * 64];
    __shared__ alignas(16) short Bs[128 * 64];
    const int tid = threadIdx.x;
    const int w = tid >> 6, lane = tid & 63, quad = lane >> 4, l15 = lane & 15;
    const int rw = (w >> 1) * 32, cw = (w & 1) * 64;
    const int m0 = blockIdx.y * 64, n0 = blockIdx.x * 128;
    f32x4 acc[2][4];
#pragma unroll
    for (int i = 0; i < 2; ++i)
#pragma unroll
        for (int j = 0; j < 4; ++j) acc[i][j] = (f32x4){0.f, 0.f, 0.f, 0.f};
    for (int k0 = 0; k0 < K; k0 += 64) {
#pragma unroll
        for (int r = 0; r < 2; ++r) {
            int idx = r * 256 + tid;
            int row = idx >> 3, cbp = idx & 7;
            int col = ((cbp ^ (row & 7)) << 3);
            *(bf16x8*)&As[row * 64 + cbp * 8] = *(const bf16x8*)&A[(size_t)(m0 + row) * K + k0 + col];
        }
#pragma unroll
        for (int r = 0; r < 4; ++r) {
            int idx = r * 256 + tid;
            int row = idx >> 3, cbp = idx & 7;
            int col = ((cbp ^ (row & 7)) << 3);
            *(bf16x8*)&Bs[row * 64 + cbp * 8] = *(const bf16x8*)&W[(size_t)(n0 + row) * K + k0 + col];
        }
        __syncthreads();
#pragma unroll
        for (int kb = 0; kb < 2; ++kb) {
            bf16x8 af[2], bfr[4];
            int cb = kb * 4 + quad;
#pragma unroll
            for (int i = 0; i < 2; ++i) {
                int row = rw + i * 16 + l15;
                af[i] = *(const bf16x8*)&As[row * 64 + ((cb ^ (row & 7)) << 3)];
            }
#pragma unroll
            for (int j = 0; j < 4; ++j) {
                int row = cw + j * 16 + l15;
                bfr[j] = *(const bf16x8*)&Bs[row * 64 + ((cb ^ (row & 7)) << 3)];
            }
#pragma unroll
            for (int i = 0; i < 2; ++i)
#pragma unroll
                for (int j = 0; j < 4; ++j)
                    acc[i][j] = __builtin_amdgcn_mfma_f32_16x16x32_bf16(af[i], bfr[j], acc[i][j], 0, 0, 0);
        }
        __syncthreads();
    }
#pragma unroll
    for (int j = 0; j < 4; ++j) {
        int n = n0 + cw + j * 16 + l15;
        float bv = bias[n];
#pragma unroll
        for (int i = 0; i < 2; ++i)
#pragma unroll
            for (int r = 0; r < 4; ++r) {
                int m = m0 + rw + i * 16 + quad * 4 + r;
                float v = acc[i][j][r] + bv;
                if (relu) v = fmaxf(v, 0.f);
                Cb[(size_t)m * N + n] = f2b(v);
            }
    }
}

// ---------------------------------------------------------------------------
// Chain tails + FUSED row-normalize. z=0: FI2B@l3 (K=256) -> FIB,FINB;
// z=1: FT1B@tl2 (K=128) -> FTB,FTNB. N=128.
// ---------------------------------------------------------------------------
__global__ __launch_bounds__(256) void gemm34n(const unsigned short* __restrict__ FI2B,
                                               const unsigned short* __restrict__ FT1B,
                                               const unsigned short* __restrict__ WB,
                                               const float* __restrict__ l3_b,
                                               const float* __restrict__ tl2_b,
                                               unsigned short* __restrict__ FIB,
                                               unsigned short* __restrict__ FTB,
                                               unsigned short* __restrict__ FINB,
                                               unsigned short* __restrict__ FTNB) {
    __shared__ alignas(16) short As[128 * 64];
    __shared__ alignas(16) short Bs[128 * 64];
    __shared__ float rowss[128];
    const int tid = threadIdx.x;
    if (tid < 128) rowss[tid] = 0.f;
    const int z = blockIdx.z;
    const unsigned short* A = z ? FT1B : FI2B;
    const unsigned short* W = z ? (WB + 1212416) : (WB + 1179648);
    const float* bias = z ? tl2_b : l3_b;
    unsigned short* Cb = z ? FTB : FIB;
    unsigned short* CN = z ? FTNB : FINB;
    const int K = z ? 128 : 256;
    const int w = tid >> 6, lane = tid & 63, quad = lane >> 4, l15 = lane & 15;
    const int rw = (w >> 1) * 64, cw = (w & 1) * 64;
    const int m0 = blockIdx.y * 128;
    f32x4 acc[4][4];
#pragma unroll
    for (int i = 0; i < 4; ++i)
#pragma unroll
        for (int j = 0; j < 4; ++j) acc[i][j] = (f32x4){0.f, 0.f, 0.f, 0.f};
    mfma_loop(A, W, K, m0, 0, As, Bs, acc);
    float bv[4];
#pragma unroll
    for (int j = 0; j < 4; ++j) bv[j] = bias[cw + j * 16 + l15];
#pragma unroll
    for (int i = 0; i < 4; ++i)
#pragma unroll
        for (int r = 0; r < 4; ++r) {
            float ssp = 0.f;
#pragma unroll
            for (int j = 0; j < 4; ++j) {
                float v = acc[i][j][r] + bv[j];
                ssp += v * v;
            }
#pragma unroll
            for (int m = 1; m < 16; m <<= 1) ssp += __shfl_xor(ssp, m);
            if (l15 == 0) atomicAdd(&rowss[rw + i * 16 + quad * 4 + r], ssp);
        }
    __syncthreads();
#pragma unroll
    for (int i = 0; i < 4; ++i)
#pragma unroll
        for (int r = 0; r < 4; ++r) {
            int lrow = rw + i * 16 + quad * 4 + r;
            float inv = 1.f / fmaxf(sqrtf(rowss[lrow]), 1e-12f);
#pragma unroll
            for (int j = 0; j < 4; ++j) {
                int n = cw + j * 16 + l15;
                float v = acc[i][j][r] + bv[j];
                Cb[(size_t)(m0 + lrow) * 128 + n] = f2b(v);
                CN[(size_t)(m0 + lrow) * 128 + n] = f2b(v * inv);
            }
        }
}

// ---------------------------------------------------------------------------
// SS heads + FUSED rownorm (z=1,2) + FUSED scalar head dot.
// ---------------------------------------------------------------------------
__global__ __launch_bounds__(256) void heads4f(const unsigned short* __restrict__ FIB,
                                               const unsigned short* __restrict__ FTB,
                                               const unsigned short* __restrict__ WB,
                                               const float* __restrict__ bisp, const float* __restrict__ bish,
                                               const float* __restrict__ btsh, const float* __restrict__ btsp,
                                               const float* __restrict__ c1w, const float* __restrict__ c2w,
                                               const float* __restrict__ c3w, const float* __restrict__ c4w,
                                               const float* __restrict__ c1b, const float* __restrict__ c2b,
                                               const float* __restrict__ c3b, const float* __restrict__ c4b,
                                               float* __restrict__ ISP, float* __restrict__ ISH,
                                               float* __restrict__ TSH, float* __restrict__ TSP,
                                               unsigned short* __restrict__ ISHN,
                                               unsigned short* __restrict__ TSHN,
                                               float* __restrict__ out) {
    __shared__ alignas(16) short As[128 * 64];
    __shared__ alignas(16) short Bs[128 * 64];
    __shared__ float rowss[128];
    __shared__ float rowdot[128];
    const int tid = threadIdx.x;
    if (tid < 128) { rowss[tid] = 0.f; rowdot[tid] = 0.f; }
    const int z = blockIdx.z;
    const unsigned short* A = (z < 2) ? FIB : FTB;
    const unsigned short* W = WB + (z == 0 ? 1228800 : z == 1 ? 1245184 : z == 2 ? 1261568 : 1277952);
    const float* bias = z == 0 ? bisp : z == 1 ? bish : z == 2 ? btsh : btsp;
    const float* hw = z == 0 ? c1w : z == 1 ? c2w : z == 2 ? c3w : c4w;
    const float* hb = z == 0 ? c1b : z == 1 ? c2b : z == 2 ? c3b : c4b;
    float* Cf = z == 0 ? ISP : z == 1 ? ISH : z == 2 ? TSH : TSP;
    unsigned short* CN = z == 1 ? ISHN : z == 2 ? TSHN : nullptr;
    const int outoff = z == 0 ? 0 : z == 1 ? 1 : z == 2 ? 3 : 2;
    const int do_norm = (z == 1 || z == 2);
    const int w = tid >> 6, lane = tid & 63, quad = lane >> 4, l15 = lane & 15;
    const int rw = (w >> 1) * 64, cw = (w & 1) * 64;
    const int m0 = blockIdx.y * 128;
    f32x4 acc[4][4];
#pragma unroll
    for (int i = 0; i < 4; ++i)
#pragma unroll
        for (int j = 0; j < 4; ++j) acc[i][j] = (f32x4){0.f, 0.f, 0.f, 0.f};
    mfma_loop(A, W, 128, m0, 0, As, Bs, acc);
    float bv[4], wv[4];
#pragma unroll
    for (int j = 0; j < 4; ++j) {
        int n = cw + j * 16 + l15;
        bv[j] = bias[n];
        wv[j] = hw[n];
    }
#pragma unroll
    for (int i = 0; i < 4; ++i)
#pragma unroll
        for (int r = 0; r < 4; ++r) {
            float ssp = 0.f, dp = 0.f;
#pragma unroll
            for (int j = 0; j < 4; ++j) {
                float v = acc[i][j][r] + bv[j];
                ssp += v * v;
                dp += v * wv[j];
            }
#pragma unroll
            for (int m = 1; m < 16; m <<= 1) {
                ssp += __shfl_xor(ssp, m);
                dp += __shfl_xor(dp, m);
            }
            if (l15 == 0) {
                int lrow = rw + i * 16 + quad * 4 + r;
                atomicAdd(&rowdot[lrow], dp);
                if (do_norm) atomicAdd(&rowss[lrow], ssp);
            }
        }
    __syncthreads();
#pragma unroll
    for (int i = 0; i < 4; ++i)
#pragma unroll
        for (int r = 0; r < 4; ++r) {
            int lrow = rw + i * 16 + quad * 4 + r;
            float inv = do_norm ? (1.f / fmaxf(sqrtf(rowss[lrow]), 1e-12f)) : 0.f;
#pragma unroll
            for (int j = 0; j < 4; ++j) {
                int n = cw + j * 16 + l15;
                float v = acc[i][j][r] + bv[j];
                Cf[(size_t)(m0 + lrow) * 128 + n] = v;
                if (do_norm) CN[(size_t)(m0 + lrow) * 128 + n] = f2b(v * inv);
            }
        }
    if (tid < 128) out[1 + (size_t)outoff * BSZ + m0 + tid] = rowdot[tid] + hb[0];
}

// ---------------------------------------------------------------------------
// MFMA CLIP tile (z=2 merged): R7-proven butterfly epilogue; ST stores use
// the TRANSPOSED [row][64 part] layout for coalesced finalize loads.
// DO NOT: transpose-reduce (R6 VGPR blowup) / LDS same-addr atomics (R8).
// ---------------------------------------------------------------------------
__global__ __launch_bounds__(256) void clip_mfma(const unsigned short* __restrict__ In1,
                                                 const unsigned short* __restrict__ Tn1,
                                                 const unsigned short* __restrict__ In2,
                                                 const unsigned short* __restrict__ Tn2,
                                                 const int* __restrict__ y,
                                                 const float* __restrict__ scale_log1,
                                                 const float* __restrict__ scale_log2,
                                                 float* __restrict__ st1, float* __restrict__ st2) {
    __shared__ alignas(16) short As[128 * 64];
    __shared__ alignas(16) short Bs[128 * 64];
    const int z = blockIdx.z;
    const unsigned short* In = z ? In2 : In1;
    const unsigned short* Tn = z ? Tn2 : Tn1;
    const float* scale_log = z ? scale_log2 : scale_log1;
    float* st = z ? st2 : st1;
    const int tid = threadIdx.x;
    const int w = tid >> 6, lane = tid & 63, quad = lane >> 4, l15 = lane & 15;
    const int bx = blockIdx.x, by = blockIdx.y;
    const int r0 = by * 128, c0 = bx * 128;
    const int rw = (w >> 1) * 64, cw = (w & 1) * 64;
    f32x4 acc[4][4];
#pragma unroll
    for (int i = 0; i < 4; ++i)
#pragma unroll
        for (int j = 0; j < 4; ++j) acc[i][j] = (f32x4){0.f, 0.f, 0.f, 0.f};
    mfma_loop(In, Tn, 128, r0, c0, As, Bs, acc);

    const float s = expf(scale_log[0]);
    int yrow[4][4]; float mrow[4][4];
    int ycol[4];    float mcol[4];
#pragma unroll
    for (int i = 0; i < 4; ++i)
#pragma unroll
        for (int r = 0; r < 4; ++r) {
            int yy = y[r0 + rw + i * 16 + quad * 4 + r];
            yrow[i][r] = yy; mrow[i][r] = (yy == 0) ? 1.f : 0.f;
        }
#pragma unroll
    for (int j = 0; j < 4; ++j) {
        int yy = y[c0 + cw + j * 16 + l15];
        ycol[j] = yy; mcol[j] = (yy == 0) ? 1.f : 0.f;
    }
    float rZ[4][4] = {}, rF[4][4] = {}, rW[4][4] = {};
    float cZ[4] = {}, cE[4] = {}, cW[4] = {};
    float aAll = 0.f, aC0 = 0.f, aR0 = 0.f, aRC = 0.f;
#pragma unroll
    for (int i = 0; i < 4; ++i)
#pragma unroll
        for (int r = 0; r < 4; ++r) {
            float mr = mrow[i][r];
            int yr = yrow[i][r];
#pragma unroll
            for (int j = 0; j < 4; ++j) {
                float S = acc[i][j][r];
                float L = s * S;
                float e1 = __expf(L);
                float e2 = __expf(S);
                float msk = (yr == ycol[j]) ? 1.f : 0.f;
                rZ[i][r] += e1; rF[i][r] += e1 * L; rW[i][r] += e1 * msk;
                cZ[j] += e2;    cE[j] += e2 * S;    cW[j] += e2 * msk;
                float tmp = S * mcol[j];
                aAll += S; aC0 += tmp; aR0 += S * mr; aRC += tmp * mr;
            }
        }
    // row partials: butterfly over the 16 lanes of each quad; guarded store
    const int p_row = bx * 2 + (cw >> 6);
#pragma unroll
    for (int i = 0; i < 4; ++i)
#pragma unroll
        for (int r = 0; r < 4; ++r) {
#pragma unroll
            for (int m = 1; m < 16; m <<= 1) {
                rZ[i][r] += __shfl_xor(rZ[i][r], m);
                rF[i][r] += __shfl_xor(rF[i][r], m);
                rW[i][r] += __shfl_xor(rW[i][r], m);
            }
            if (l15 == (i * 4 + r)) {
                int grow = r0 + rw + i * 16 + quad * 4 + r;
                int base = ST_ROW + grow * 64 + p_row;
                st[base]          = rZ[i][r];
                st[base + 262144] = rF[i][r];
                st[base + 524288] = rW[i][r];
            }
        }
    // col partials: reduce across quads
    const int p_col = by * 2 + (rw >> 6);
#pragma unroll
    for (int j = 0; j < 4; ++j) {
        cZ[j] += __shfl_xor(cZ[j], 16); cZ[j] += __shfl_xor(cZ[j], 32);
        cE[j] += __shfl_xor(cE[j], 16); cE[j] += __shfl_xor(cE[j], 32);
        cW[j] += __shfl_xor(cW[j], 16); cW[j] += __shfl_xor(cW[j], 32);
        if (quad == 0) {
            int gcol = c0 + cw + j * 16 + l15;
            int base = ST_COL + gcol * 64 + p_col;
            st[base]          = cZ[j];
            st[base + 262144] = cE[j];
            st[base + 524288] = cW[j];
        }
    }
    // T scalars: per-wave reduce + store
#pragma unroll
    for (int m = 1; m < 64; m <<= 1) {
        aAll += __shfl_xor(aAll, m); aC0 += __shfl_xor(aC0, m);
        aR0 += __shfl_xor(aR0, m);   aRC += __shfl_xor(aRC, m);
    }
    if (lane == 0) {
        int wg = (by * 32 + bx) * 4 + w;
        float T00 = aRC, T01 = aR0 - aRC, T10 = aC0 - aRC, T11 = aAll - aR0 - aC0 + aRC;
        st[ST_T + wg * 4 + 0] = T00;
        st[ST_T + wg * 4 + 1] = T01;
        st[ST_T + wg * 4 + 2] = T10;
        st[ST_T + wg * 4 + 3] = T11;
    }
}

// ---------------------------------------------------------------------------
// post: y<2 -> clip finalize (COALESCED loads: lane=partial, unit stride);
//       y==2, x<256 -> gram split-K. Independent workloads, one launch.
// ---------------------------------------------------------------------------
__global__ __launch_bounds__(256) void post_kernel(const float* __restrict__ st1,
                                                   const float* __restrict__ st2,
                                                   const int* __restrict__ y,
                                                   float* __restrict__ RV,
                                                   float* __restrict__ TT,
                                                   const float* __restrict__ isp,
                                                   const float* __restrict__ ish,
                                                   const float* __restrict__ tsp,
                                                   const float* __restrict__ tsh,
                                                   float* __restrict__ GP) {
    __shared__ alignas(16) float sh[64 * 128];   // 32 KB union
    const int tid = threadIdx.x;
    if (blockIdx.y == 2) {
        if (blockIdx.x >= 256) return;
        float (*As2)[128] = (float(*)[128])sh;
        const int mat = blockIdx.x >> 6, chunk = blockIdx.x & 63;
        const float* A = mat == 0 ? isp : mat == 1 ? ish : mat == 2 ? tsp : tsh;
        const int m0 = chunk * 64;
#pragma unroll
        for (int r = 0; r < 8; ++r) {
            int idx = r * 256 + tid;
            int row = idx >> 5, c4 = (idx & 31) * 4;
            *(float4*)&As2[row][c4] = *(const float4*)&A[(size_t)(m0 + row) * 128 + c4];
        }
        __syncthreads();
        const int ty = tid >> 4, tx = tid & 15;
        float acc[8][8] = {};
        for (int k = 0; k < 64; ++k) {
            float av[8], bv[8];
            *(float4*)&av[0] = *(const float4*)&As2[k][ty * 8];
            *(float4*)&av[4] = *(const float4*)&As2[k][ty * 8 + 4];
            *(float4*)&bv[0] = *(const float4*)&As2[k][tx * 8];
            *(float4*)&bv[4] = *(const float4*)&As2[k][tx * 8 + 4];
#pragma unroll
            for (int i = 0; i < 8; ++i)
#pragma unroll
                for (int j = 0; j < 8; ++j) acc[i][j] += av[i] * bv[j];
        }
        float* Gp = GP + ((size_t)(mat * 64 + chunk) << 14);
#pragma unroll
        for (int i = 0; i < 8; ++i) {
            *(float4*)&Gp[(ty * 8 + i) * 128 + tx * 8]     = *(float4*)&acc[i][0];
            *(float4*)&Gp[(ty * 8 + i) * 128 + tx * 8 + 4] = *(float4*)&acc[i][4];
        }
        return;
    }
    // finalize
    float* cred = sh;                       // 256
    float4* tred = (float4*)(sh + 256);     // 256 float4
    const int z = blockIdx.y;
    const float* st = z ? st2 : st1;
    const int lane = tid & 63;
    const int k = blockIdx.x * 4 + (tid >> 6);
    const float Bf = (float)BSZ;

    float ccnt = 0.f;
    for (int i = tid; i < BSZ; i += 256) ccnt += (y[i] == 0) ? 1.f : 0.f;
    cred[tid] = ccnt;
    __syncthreads();
    for (int ss2 = 128; ss2 > 0; ss2 >>= 1) {
        if (tid < ss2) cred[tid] += cred[tid + ss2];
        __syncthreads();
    }
    const float n0 = cred[0];

    const int base = k * 64 + lane;
    float Z1 = st[ST_ROW + base];
    float F1 = st[ST_ROW + 262144 + base];
    float W1 = st[ST_ROW + 524288 + base];
    float Z2 = st[ST_COL + base];
    float E2 = st[ST_COL + 262144 + base];
    float W2 = st[ST_COL + 524288 + base];
#pragma unroll
    for (int m = 1; m < 64; m <<= 1) {
        Z1 += __shfl_xor(Z1, m); F1 += __shfl_xor(F1, m); W1 += __shfl_xor(W1, m);
        Z2 += __shfl_xor(Z2, m); E2 += __shfl_xor(E2, m); W2 += __shfl_xor(W2, m);
    }
    if (lane == 0) {
        int yk = y[k];
        float n = (yk == 0) ? n0 : (Bf - n0);
        float a = 1.0f / n;
        float ea = expf(a);
        float denom = n * ea + (Bf - n);
        float q_s = ea / denom, q_d = 1.0f / denom;
        float ld = logf(denom);
        float lq_s = a - ld, lq_d = -ld;
        float Qlq = n * q_s * lq_s + (Bf - n) * q_d * lq_d;
        float term_r = Qlq + F1 / Z1 - lq_d - (lq_s - lq_d) * (W1 / Z1);
        float term_c = Qlq + E2 / Z2 - lq_d - (lq_s - lq_d) * (W2 / Z2);
        RV[(size_t)z * BSZ + k] = (term_r + term_c) / (4.0f * Bf);
    }
    if (blockIdx.x == 0) {
        const float4* tp = (const float4*)&st[ST_T];
        float4 acc = {0.f, 0.f, 0.f, 0.f};
        for (int u = tid; u < 4096; u += 256) {
            float4 t4 = tp[u];
            acc.x += t4.x; acc.y += t4.y; acc.z += t4.z; acc.w += t4.w;
        }
        tred[tid] = acc;
        __syncthreads();
        for (int ss2 = 128; ss2 > 0; ss2 >>= 1) {
            if (tid < ss2) {
                tred[tid].x += tred[tid + ss2].x; tred[tid].y += tred[tid + ss2].y;
                tred[tid].z += tred[tid + ss2].z; tred[tid].w += tred[tid + ss2].w;
            }
            __syncthreads();
        }
        if (tid == 0) {
            TT[z * 4 + 0] = tred[0].x; TT[z * 4 + 1] = tred[0].y;
            TT[z * 4 + 2] = tred[0].z; TT[z * 4 + 3] = tred[0].w;
        }
    }
}

// frob_combine: grid (64,2), block 64 (1 wave). Each block: 256 entries.
__global__ void frob_combine(const float* __restrict__ GP, float* __restrict__ scal) {
    const int z = blockIdx.y;
    const int tid = threadIdx.x;
    int u = blockIdx.x * 256 + tid * 4;
    float4 ga = {0.f, 0.f, 0.f, 0.f};
    float4 gb = {0.f, 0.f, 0.f, 0.f};
    const size_t baseA = ((size_t)(2 * z) * 64) << 14;
    const size_t baseB = ((size_t)(2 * z + 1) * 64) << 14;
    for (int c = 0; c < 64; ++c) {
        float4 va = *(const float4*)&GP[baseA + ((size_t)c << 14) + u];
        float4 vb = *(const float4*)&GP[baseB + ((size_t)c << 14) + u];
        ga.x += va.x; ga.y += va.y; ga.z += va.z; ga.w += va.w;
        gb.x += vb.x; gb.y += vb.y; gb.z += vb.z; gb.w += vb.w;
    }
    float r = ga.x * gb.x + ga.y * gb.y + ga.z * gb.z + ga.w * gb.w;
#pragma unroll
    for (int m = 1; m < 64; m <<= 1) r += __shfl_xor(r, m);
    if (tid == 0) atomicAdd(&scal[3 + z], r);
}

// ---------------------------------------------------------------------------
// Final: sum RV per z (+ recount n0) + T tails + gram terms -> out[0]
// ---------------------------------------------------------------------------
__global__ void final_kernel(const float* __restrict__ RV, const float* __restrict__ scal,
                             const int* __restrict__ y,
                             const float* __restrict__ sl1, const float* __restrict__ sl2,
                             float* __restrict__ out) {
    __shared__ float red0[256], red1[256], red2[256];
    int tid = threadIdx.x;
    float s0 = 0.f, s1 = 0.f, cnt = 0.f;
    for (int u = tid; u < BSZ; u += 256) {
        s0 += RV[u]; s1 += RV[BSZ + u];
        cnt += (y[u] == 0) ? 1.f : 0.f;
    }
    red0[tid] = s0; red1[tid] = s1; red2[tid] = cnt;
    __syncthreads();
    for (int ss = 128; ss > 0; ss >>= 1) {
        if (tid < ss) {
            red0[tid] += red0[tid + ss]; red1[tid] += red1[tid + ss];
            red2[tid] += red2[tid + ss];
        }
        __syncthreads();
    }
    if (tid == 0) {
        const float Bf = (float)BSZ;
        float n0 = red2[0], n1 = Bf - n0;
        float e0 = expf(1.f / n0), e1 = expf(1.f / n1);
        float d0 = n0 * e0 + (Bf - n0), d1 = n1 * e1 + (Bf - n1);
        float qs0 = e0 / d0, qd0 = 1.f / d0, qs1 = e1 / d1, qd1 = 1.f / d1;
        float loss_z[2];
        for (int z = 0; z < 2; ++z) {
            float T00 = scal[8 + z * 4 + 0], T01 = scal[8 + z * 4 + 1];
            float T10 = scal[8 + z * 4 + 2], T11 = scal[8 + z * 4 + 3];
            float QS1 = qd0 * (T00 + T01) + (qs0 - qd0) * T00 + qd1 * (T10 + T11) + (qs1 - qd1) * T11;
            float QS2 = qd0 * (T00 + T10) + (qs0 - qd0) * T00 + qd1 * (T01 + T11) + (qs1 - qd1) * T11;
            float s = expf(z ? sl2[0] : sl1[0]);
            loss_z[z] = (z ? red1[0] : red0[0]) + (-s * QS1 - QS2) / (4.0f * Bf);
        }
        float loss_sp = 0.5f * (sqrtf(scal[4]) + sqrtf(scal[3]));
        out[0] = (loss_sp + loss_z[1] + loss_z[0]) / 3.0f;
    }
}

// ---------------------------------------------------------------------------
extern "C" void kernel_launch(void* const* d_in, const int* in_sizes, int n_in,
                              void* d_out, int out_size, void* d_ws, size_t ws_size,
                              hipStream_t stream) {
    const float* i_in  = (const float*)d_in[0];
    const float* t_in  = (const float*)d_in[1];
    const int*   y     = (const int*)d_in[2];
    const float* l1_w  = (const float*)d_in[3];
    const float* l1_b  = (const float*)d_in[4];
    const float* l2_w  = (const float*)d_in[5];
    const float* l2_b  = (const float*)d_in[6];
    const float* l3_w  = (const float*)d_in[7];
    const float* l3_b  = (const float*)d_in[8];
    const float* tl1_w = (const float*)d_in[9];
    const float* tl1_b = (const float*)d_in[10];
    const float* tl2_w = (const float*)d_in[11];
    const float* tl2_b = (const float*)d_in[12];
    const float* isp_w = (const float*)d_in[13];
    const float* isp_b = (const float*)d_in[14];
    const float* ish_w = (const float*)d_in[15];
    const float* ish_b = (const float*)d_in[16];
    const float* tsh_w = (const float*)d_in[17];
    const float* tsh_b = (const float*)d_in[18];
    const float* tsp_w = (const float*)d_in[19];
    const float* tsp_b = (const float*)d_in[20];
    const float* c1_w  = (const float*)d_in[21];
    const float* c1_b  = (const float*)d_in[22];
    const float* c2_w  = (const float*)d_in[23];
    const float* c2_b  = (const float*)d_in[24];
    const float* c3_w  = (const float*)d_in[25];
    const float* c3_b  = (const float*)d_in[26];
    const float* c4_w  = (const float*)d_in[27];
    const float* c4_b  = (const float*)d_in[28];
    const float* scale1 = (const float*)d_in[29];
    const float* scale2 = (const float*)d_in[30];

    float* ws = (float*)d_ws;
    float* SCAL = ws;                       // 64 (zeroed; [3],[4] frob; [8..15] T)
    float* RV   = ws + 64;                  // 2*4096
    float* ISP  = RV + 2 * BSZ;
    float* ISH  = ISP + (size_t)BSZ * 128;
    float* TSP  = ISH + (size_t)BSZ * 128;
    float* TSH  = TSP + (size_t)BSZ * 128;
    unsigned short* IB   = (unsigned short*)(TSH + (size_t)BSZ * 128);
    unsigned short* WB   = IB + (size_t)BSZ * 2048;      // 1294336
    unsigned short* FI1B = WB + 1294336;
    unsigned short* FI2B = FI1B + (size_t)BSZ * 512;
    unsigned short* FIB  = FI2B + (size_t)BSZ * 256;
    unsigned short* FT1B = FIB + (size_t)BSZ * 128;
    unsigned short* FTB  = FT1B + (size_t)BSZ * 128;
    unsigned short* FINB = FTB + (size_t)BSZ * 128;
    unsigned short* FTNB = FINB + (size_t)BSZ * 128;
    unsigned short* ISHN = FTNB + (size_t)BSZ * 128;
    unsigned short* TSHN = ISHN + (size_t)BSZ * 128;
    // ST (2 x 6.36 MB) aliases IB head; GP (16.8 MB) starts AFTER ST2 so the
    // merged post_kernel can read ST while writing GP (no overlap). GP spans
    // the dead IB tail + WB..TSHN region (all consumed before post runs).
    float* ST1 = (float*)IB;
    float* ST2 = ST1 + ST_FLOATS;
    float* GP  = ST2 + ST_FLOATS;

    float* out = (float*)d_out;

    hipMemsetAsync(d_ws, 0, 64 * sizeof(float), stream);
    prep_kernel<<<9584, 256, 0, stream>>>(i_in, l1_w, l2_w, l3_w, tl2_w, isp_w, ish_w, tsh_w, tsp_w,
                                          IB, t_in, tl1_w, tl1_b, FT1B);
    mfma_gemm64<<<dim3(4, 64), 256, 0, stream>>>(IB, WB, l1_b, FI1B, 512, 2048, 1);
    mfma_gemm64<<<dim3(2, 64), 256, 0, stream>>>(FI1B, WB + 1048576, l2_b, FI2B, 256, 512, 1);
    gemm34n<<<dim3(1, 32, 2), 256, 0, stream>>>(FI2B, FT1B, WB, l3_b, tl2_b, FIB, FTB, FINB, FTNB);
    heads4f<<<dim3(1, 32, 4), 256, 0, stream>>>(FIB, FTB, WB, isp_b, ish_b, tsh_b, tsp_b,
                                                c1_w, c2_w, c3_w, c4_w, c1_b, c2_b, c3_b, c4_b,
                                                ISP, ISH, TSH, TSP, ISHN, TSHN, out);
    clip_mfma<<<dim3(32, 32, 2), 256, 0, stream>>>(FINB, FTNB, ISHN, TSHN, y, scale1, scale2, ST1, ST2);
    post_kernel<<<dim3(1024, 3), 256, 0, stream>>>(ST1, ST2, y, RV, &SCAL[8], ISP, ISH, TSP, TSH, GP);
    frob_combine<<<dim3(64, 2), 64, 0, stream>>>(GP, SCAL);
    final_kernel<<<1, 256, 0, stream>>>(RV, SCAL, y, scale1, scale2, out);
}

// Round 11
// 289.903 us; speedup vs baseline: 1.7014x; 1.0588x over previous
//
#include <hip/hip_runtime.h>
#include <math.h>

#define BSZ 4096

typedef __attribute__((ext_vector_type(8))) short bf16x8;
typedef __attribute__((ext_vector_type(4))) float f32x4;

// ST layout (floats), TRANSPOSED for coalesced finalize loads:
//   rowZ@0, rowF@262144, rowW@524288   each [4096 row][64 part]
//   colZ@786432, colE@1048576, colW@1310720  each [4096 col][64 part]
//   Tpart@1572864 ([4096 waves][4])
#define ST_ROW 0
#define ST_COL 786432
#define ST_T   1572864
#define ST_FLOATS 1589248

__device__ __forceinline__ unsigned short f2b(float f) {
    unsigned u = __float_as_uint(f);
    u = u + 0x7fffu + ((u >> 16) & 1u);
    return (unsigned short)(u >> 16);
}
__device__ __forceinline__ float b2f(unsigned short s) {
    return __uint_as_float(((unsigned)s) << 16);
}

// DPP add: x += lane-permuted x (pure VALU, no DS pipe).
// CTRL: 0xB1=quad_perm xor1, 0x4E=quad_perm xor2, 0x124=row_ror:4, 0x128=row_ror:8
template <int CTRL>
__device__ __forceinline__ float dpp_add(float x) {
    int p = __builtin_amdgcn_update_dpp(0, __float_as_int(x), CTRL, 0xF, 0xF, true);
    return x + __int_as_float(p);
}
// All-reduce sum across each 16-lane row (all lanes get the total).
__device__ __forceinline__ float sum16(float x) {
    x = dpp_add<0xB1>(x);
    x = dpp_add<0x4E>(x);
    x = dpp_add<0x124>(x);
    x = dpp_add<0x128>(x);
    return x;
}

// ---------------------------------------------------------------------------
// prep: blocks <9456 cast i+weights -> bf16 IB|WB; blocks >=9456 run the
// tl1 SIMT GEMM (K=49, fp32 in, bf16 out). Independent work, one launch.
// ---------------------------------------------------------------------------
__global__ void prep_kernel(const float* __restrict__ i_in,
                            const float* __restrict__ l1, const float* __restrict__ l2,
                            const float* __restrict__ l3, const float* __restrict__ tl2,
                            const float* __restrict__ isp, const float* __restrict__ ish,
                            const float* __restrict__ tsh, const float* __restrict__ tsp,
                            unsigned short* __restrict__ o,
                            const float* __restrict__ t_in, const float* __restrict__ tl1_w,
                            const float* __restrict__ tl1_b, unsigned short* __restrict__ FT1B) {
    __shared__ float As[16][65];
    __shared__ float Ws[16][65];
    if (blockIdx.x < 9456) {
        int i = (blockIdx.x * 256 + threadIdx.x) * 4;
        if (i >= 9682944) return;
        const float* src; int off;
        if (i < 8388608)      { src = i_in; off = 0; }
        else if (i < 9437184) { src = l1;  off = 8388608; }
        else if (i < 9568256) { src = l2;  off = 9437184; }
        else if (i < 9601024) { src = l3;  off = 9568256; }
        else if (i < 9617408) { src = tl2; off = 9601024; }
        else if (i < 9633792) { src = isp; off = 9617408; }
        else if (i < 9650176) { src = ish; off = 9633792; }
        else if (i < 9666560) { src = tsh; off = 9650176; }
        else                  { src = tsp; off = 9666560; }
        float4 v = *(const float4*)(src + (i - off));
        ushort4 r;
        r.x = f2b(v.x); r.y = f2b(v.y); r.z = f2b(v.z); r.w = f2b(v.w);
        *(ushort4*)(o + i) = r;
        return;
    }
    const int b = blockIdx.x - 9456;
    const int tid = threadIdx.x;
    const int tx = tid & 15, ty = tid >> 4;
    const int m0 = (b >> 1) * 64, n0 = (b & 1) * 64;
    const int K = 49, N = 128;
    float acc[4][4] = {};
    const int lrow = tid >> 2;
    const int lkb = (tid & 3) * 4;
    for (int k0 = 0; k0 < K; k0 += 16) {
#pragma unroll
        for (int u = 0; u < 4; ++u) {
            int k = k0 + lkb + u;
            As[lkb + u][lrow] = (k < K) ? t_in[(size_t)(m0 + lrow) * K + k] : 0.0f;
            Ws[lkb + u][lrow] = (k < K) ? tl1_w[(size_t)(n0 + lrow) * K + k] : 0.0f;
        }
        __syncthreads();
#pragma unroll
        for (int kk = 0; kk < 16; ++kk) {
            float av[4], bv[4];
#pragma unroll
            for (int i = 0; i < 4; ++i) av[i] = As[kk][ty * 4 + i];
#pragma unroll
            for (int j = 0; j < 4; ++j) bv[j] = Ws[kk][tx * 4 + j];
#pragma unroll
            for (int i = 0; i < 4; ++i)
#pragma unroll
                for (int j = 0; j < 4; ++j) acc[i][j] += av[i] * bv[j];
        }
        __syncthreads();
    }
#pragma unroll
    for (int i = 0; i < 4; ++i)
#pragma unroll
        for (int j = 0; j < 4; ++j) {
            int n = n0 + tx * 4 + j;
            float v = fmaxf(acc[i][j] + tl1_b[n], 0.0f);
            FT1B[(size_t)(m0 + ty * 4 + i) * N + n] = f2b(v);
        }
}

// ---------------------------------------------------------------------------
// Shared MFMA tile loop (128-row tiles): acc = A @ W^T, 4 waves, BK=64.
// ---------------------------------------------------------------------------
__device__ __forceinline__ void mfma_loop(const unsigned short* __restrict__ A,
                                          const unsigned short* __restrict__ W,
                                          int K, int m0, int n0,
                                          short* As, short* Bs, f32x4 (&acc)[4][4]) {
    const int tid = threadIdx.x;
    const int w = tid >> 6, lane = tid & 63, quad = lane >> 4, l15 = lane & 15;
    const int rw = (w >> 1) * 64, cw = (w & 1) * 64;
    for (int k0 = 0; k0 < K; k0 += 64) {
#pragma unroll
        for (int r = 0; r < 4; ++r) {
            int idx = r * 256 + tid;
            int row = idx >> 3, cbp = idx & 7;
            int col = ((cbp ^ (row & 7)) << 3);
            *(bf16x8*)&As[row * 64 + cbp * 8] = *(const bf16x8*)&A[(size_t)(m0 + row) * K + k0 + col];
            *(bf16x8*)&Bs[row * 64 + cbp * 8] = *(const bf16x8*)&W[(size_t)(n0 + row) * K + k0 + col];
        }
        __syncthreads();
#pragma unroll
        for (int kb = 0; kb < 2; ++kb) {
            bf16x8 af[4], bfr[4];
            int cb = kb * 4 + quad;
#pragma unroll
            for (int i = 0; i < 4; ++i) {
                int row = rw + i * 16 + l15;
                af[i] = *(const bf16x8*)&As[row * 64 + ((cb ^ (row & 7)) << 3)];
            }
#pragma unroll
            for (int j = 0; j < 4; ++j) {
                int row = cw + j * 16 + l15;
                bfr[j] = *(const bf16x8*)&Bs[row * 64 + ((cb ^ (row & 7)) << 3)];
            }
#pragma unroll
            for (int i = 0; i < 4; ++i)
#pragma unroll
                for (int j = 0; j < 4; ++j)
                    acc[i][j] = __builtin_amdgcn_mfma_f32_16x16x32_bf16(af[i], bfr[j], acc[i][j], 0, 0, 0);
        }
        __syncthreads();
    }
}

// ---------------------------------------------------------------------------
// 64x128 M-tile MFMA GEMM (L1/L2): doubles grid occupancy vs 128-tile.
// ---------------------------------------------------------------------------
__global__ __launch_bounds__(256) void mfma_gemm64(const unsigned short* __restrict__ A,
                                                   const unsigned short* __restrict__ W,
                                                   const float* __restrict__ bias,
                                                   unsigned short* __restrict__ Cb,
                                                   int N, int K, int relu) {
    __shared__ alignas(16) short As[64 * 64];
    __shared__ alignas(16) short Bs[128 * 64];
    const int tid = threadIdx.x;
    const int w = tid >> 6, lane = tid & 63, quad = lane >> 4, l15 = lane & 15;
    const int rw = (w >> 1) * 32, cw = (w & 1) * 64;
    const int m0 = blockIdx.y * 64, n0 = blockIdx.x * 128;
    f32x4 acc[2][4];
#pragma unroll
    for (int i = 0; i < 2; ++i)
#pragma unroll
        for (int j = 0; j < 4; ++j) acc[i][j] = (f32x4){0.f, 0.f, 0.f, 0.f};
    for (int k0 = 0; k0 < K; k0 += 64) {
#pragma unroll
        for (int r = 0; r < 2; ++r) {
            int idx = r * 256 + tid;
            int row = idx >> 3, cbp = idx & 7;
            int col = ((cbp ^ (row & 7)) << 3);
            *(bf16x8*)&As[row * 64 + cbp * 8] = *(const bf16x8*)&A[(size_t)(m0 + row) * K + k0 + col];
        }
#pragma unroll
        for (int r = 0; r < 4; ++r) {
            int idx = r * 256 + tid;
            int row = idx >> 3, cbp = idx & 7;
            int col = ((cbp ^ (row & 7)) << 3);
            *(bf16x8*)&Bs[row * 64 + cbp * 8] = *(const bf16x8*)&W[(size_t)(n0 + row) * K + k0 + col];
        }
        __syncthreads();
#pragma unroll
        for (int kb = 0; kb < 2; ++kb) {
            bf16x8 af[2], bfr[4];
            int cb = kb * 4 + quad;
#pragma unroll
            for (int i = 0; i < 2; ++i) {
                int row = rw + i * 16 + l15;
                af[i] = *(const bf16x8*)&As[row * 64 + ((cb ^ (row & 7)) << 3)];
            }
#pragma unroll
            for (int j = 0; j < 4; ++j) {
                int row = cw + j * 16 + l15;
                bfr[j] = *(const bf16x8*)&Bs[row * 64 + ((cb ^ (row & 7)) << 3)];
            }
#pragma unroll
            for (int i = 0; i < 2; ++i)
#pragma unroll
                for (int j = 0; j < 4; ++j)
                    acc[i][j] = __builtin_amdgcn_mfma_f32_16x16x32_bf16(af[i], bfr[j], acc[i][j], 0, 0, 0);
        }
        __syncthreads();
    }
#pragma unroll
    for (int j = 0; j < 4; ++j) {
        int n = n0 + cw + j * 16 + l15;
        float bv = bias[n];
#pragma unroll
        for (int i = 0; i < 2; ++i)
#pragma unroll
            for (int r = 0; r < 4; ++r) {
                int m = m0 + rw + i * 16 + quad * 4 + r;
                float v = acc[i][j][r] + bv;
                if (relu) v = fmaxf(v, 0.f);
                Cb[(size_t)m * N + n] = f2b(v);
            }
    }
}

// ---------------------------------------------------------------------------
// Chain tails + FUSED row-normalize. z=0: FI2B@l3 (K=256) -> FIB,FINB;
// z=1: FT1B@tl2 (K=128) -> FTB,FTNB. N=128.
// ---------------------------------------------------------------------------
__global__ __launch_bounds__(256) void gemm34n(const unsigned short* __restrict__ FI2B,
                                               const unsigned short* __restrict__ FT1B,
                                               const unsigned short* __restrict__ WB,
                                               const float* __restrict__ l3_b,
                                               const float* __restrict__ tl2_b,
                                               unsigned short* __restrict__ FIB,
                                               unsigned short* __restrict__ FTB,
                                               unsigned short* __restrict__ FINB,
                                               unsigned short* __restrict__ FTNB) {
    __shared__ alignas(16) short As[128 * 64];
    __shared__ alignas(16) short Bs[128 * 64];
    __shared__ float rowss[128];
    const int tid = threadIdx.x;
    if (tid < 128) rowss[tid] = 0.f;
    const int z = blockIdx.z;
    const unsigned short* A = z ? FT1B : FI2B;
    const unsigned short* W = z ? (WB + 1212416) : (WB + 1179648);
    const float* bias = z ? tl2_b : l3_b;
    unsigned short* Cb = z ? FTB : FIB;
    unsigned short* CN = z ? FTNB : FINB;
    const int K = z ? 128 : 256;
    const int w = tid >> 6, lane = tid & 63, quad = lane >> 4, l15 = lane & 15;
    const int rw = (w >> 1) * 64, cw = (w & 1) * 64;
    const int m0 = blockIdx.y * 128;
    f32x4 acc[4][4];
#pragma unroll
    for (int i = 0; i < 4; ++i)
#pragma unroll
        for (int j = 0; j < 4; ++j) acc[i][j] = (f32x4){0.f, 0.f, 0.f, 0.f};
    mfma_loop(A, W, K, m0, 0, As, Bs, acc);
    float bv[4];
#pragma unroll
    for (int j = 0; j < 4; ++j) bv[j] = bias[cw + j * 16 + l15];
#pragma unroll
    for (int i = 0; i < 4; ++i)
#pragma unroll
        for (int r = 0; r < 4; ++r) {
            float ssp = 0.f;
#pragma unroll
            for (int j = 0; j < 4; ++j) {
                float v = acc[i][j][r] + bv[j];
                ssp += v * v;
            }
            ssp = sum16(ssp);
            if (l15 == 0) atomicAdd(&rowss[rw + i * 16 + quad * 4 + r], ssp);
        }
    __syncthreads();
#pragma unroll
    for (int i = 0; i < 4; ++i)
#pragma unroll
        for (int r = 0; r < 4; ++r) {
            int lrow = rw + i * 16 + quad * 4 + r;
            float inv = 1.f / fmaxf(sqrtf(rowss[lrow]), 1e-12f);
#pragma unroll
            for (int j = 0; j < 4; ++j) {
                int n = cw + j * 16 + l15;
                float v = acc[i][j][r] + bv[j];
                Cb[(size_t)(m0 + lrow) * 128 + n] = f2b(v);
                CN[(size_t)(m0 + lrow) * 128 + n] = f2b(v * inv);
            }
        }
}

// ---------------------------------------------------------------------------
// SS heads + FUSED rownorm (z=1,2) + FUSED scalar head dot.
// ---------------------------------------------------------------------------
__global__ __launch_bounds__(256) void heads4f(const unsigned short* __restrict__ FIB,
                                               const unsigned short* __restrict__ FTB,
                                               const unsigned short* __restrict__ WB,
                                               const float* __restrict__ bisp, const float* __restrict__ bish,
                                               const float* __restrict__ btsh, const float* __restrict__ btsp,
                                               const float* __restrict__ c1w, const float* __restrict__ c2w,
                                               const float* __restrict__ c3w, const float* __restrict__ c4w,
                                               const float* __restrict__ c1b, const float* __restrict__ c2b,
                                               const float* __restrict__ c3b, const float* __restrict__ c4b,
                                               float* __restrict__ ISP, float* __restrict__ ISH,
                                               float* __restrict__ TSH, float* __restrict__ TSP,
                                               unsigned short* __restrict__ ISHN,
                                               unsigned short* __restrict__ TSHN,
                                               float* __restrict__ out) {
    __shared__ alignas(16) short As[128 * 64];
    __shared__ alignas(16) short Bs[128 * 64];
    __shared__ float rowss[128];
    __shared__ float rowdot[128];
    const int tid = threadIdx.x;
    if (tid < 128) { rowss[tid] = 0.f; rowdot[tid] = 0.f; }
    const int z = blockIdx.z;
    const unsigned short* A = (z < 2) ? FIB : FTB;
    const unsigned short* W = WB + (z == 0 ? 1228800 : z == 1 ? 1245184 : z == 2 ? 1261568 : 1277952);
    const float* bias = z == 0 ? bisp : z == 1 ? bish : z == 2 ? btsh : btsp;
    const float* hw = z == 0 ? c1w : z == 1 ? c2w : z == 2 ? c3w : c4w;
    const float* hb = z == 0 ? c1b : z == 1 ? c2b : z == 2 ? c3b : c4b;
    float* Cf = z == 0 ? ISP : z == 1 ? ISH : z == 2 ? TSH : TSP;
    unsigned short* CN = z == 1 ? ISHN : z == 2 ? TSHN : nullptr;
    const int outoff = z == 0 ? 0 : z == 1 ? 1 : z == 2 ? 3 : 2;
    const int do_norm = (z == 1 || z == 2);
    const int w = tid >> 6, lane = tid & 63, quad = lane >> 4, l15 = lane & 15;
    const int rw = (w >> 1) * 64, cw = (w & 1) * 64;
    const int m0 = blockIdx.y * 128;
    f32x4 acc[4][4];
#pragma unroll
    for (int i = 0; i < 4; ++i)
#pragma unroll
        for (int j = 0; j < 4; ++j) acc[i][j] = (f32x4){0.f, 0.f, 0.f, 0.f};
    mfma_loop(A, W, 128, m0, 0, As, Bs, acc);
    float bv[4], wv[4];
#pragma unroll
    for (int j = 0; j < 4; ++j) {
        int n = cw + j * 16 + l15;
        bv[j] = bias[n];
        wv[j] = hw[n];
    }
#pragma unroll
    for (int i = 0; i < 4; ++i)
#pragma unroll
        for (int r = 0; r < 4; ++r) {
            float ssp = 0.f, dp = 0.f;
#pragma unroll
            for (int j = 0; j < 4; ++j) {
                float v = acc[i][j][r] + bv[j];
                ssp += v * v;
                dp += v * wv[j];
            }
            ssp = sum16(ssp);
            dp = sum16(dp);
            if (l15 == 0) {
                int lrow = rw + i * 16 + quad * 4 + r;
                atomicAdd(&rowdot[lrow], dp);
                if (do_norm) atomicAdd(&rowss[lrow], ssp);
            }
        }
    __syncthreads();
#pragma unroll
    for (int i = 0; i < 4; ++i)
#pragma unroll
        for (int r = 0; r < 4; ++r) {
            int lrow = rw + i * 16 + quad * 4 + r;
            float inv = do_norm ? (1.f / fmaxf(sqrtf(rowss[lrow]), 1e-12f)) : 0.f;
#pragma unroll
            for (int j = 0; j < 4; ++j) {
                int n = cw + j * 16 + l15;
                float v = acc[i][j][r] + bv[j];
                Cf[(size_t)(m0 + lrow) * 128 + n] = v;
                if (do_norm) CN[(size_t)(m0 + lrow) * 128 + n] = f2b(v * inv);
            }
        }
    if (tid < 128) out[1 + (size_t)outoff * BSZ + m0 + tid] = rowdot[tid] + hb[0];
}

// ---------------------------------------------------------------------------
// MFMA CLIP tile (z=2 merged): R7-proven structure; intra-16 reductions now
// via DPP (VALU) instead of shfl (DS pipe) — semantics identical (all-reduce),
// guard logic and register pressure unchanged.
// ---------------------------------------------------------------------------
__global__ __launch_bounds__(256) void clip_mfma(const unsigned short* __restrict__ In1,
                                                 const unsigned short* __restrict__ Tn1,
                                                 const unsigned short* __restrict__ In2,
                                                 const unsigned short* __restrict__ Tn2,
                                                 const int* __restrict__ y,
                                                 const float* __restrict__ scale_log1,
                                                 const float* __restrict__ scale_log2,
                                                 float* __restrict__ st1, float* __restrict__ st2) {
    __shared__ alignas(16) short As[128 * 64];
    __shared__ alignas(16) short Bs[128 * 64];
    const int z = blockIdx.z;
    const unsigned short* In = z ? In2 : In1;
    const unsigned short* Tn = z ? Tn2 : Tn1;
    const float* scale_log = z ? scale_log2 : scale_log1;
    float* st = z ? st2 : st1;
    const int tid = threadIdx.x;
    const int w = tid >> 6, lane = tid & 63, quad = lane >> 4, l15 = lane & 15;
    const int bx = blockIdx.x, by = blockIdx.y;
    const int r0 = by * 128, c0 = bx * 128;
    const int rw = (w >> 1) * 64, cw = (w & 1) * 64;
    f32x4 acc[4][4];
#pragma unroll
    for (int i = 0; i < 4; ++i)
#pragma unroll
        for (int j = 0; j < 4; ++j) acc[i][j] = (f32x4){0.f, 0.f, 0.f, 0.f};
    mfma_loop(In, Tn, 128, r0, c0, As, Bs, acc);

    const float s = expf(scale_log[0]);
    int yrow[4][4]; float mrow[4][4];
    int ycol[4];    float mcol[4];
#pragma unroll
    for (int i = 0; i < 4; ++i)
#pragma unroll
        for (int r = 0; r < 4; ++r) {
            int yy = y[r0 + rw + i * 16 + quad * 4 + r];
            yrow[i][r] = yy; mrow[i][r] = (yy == 0) ? 1.f : 0.f;
        }
#pragma unroll
    for (int j = 0; j < 4; ++j) {
        int yy = y[c0 + cw + j * 16 + l15];
        ycol[j] = yy; mcol[j] = (yy == 0) ? 1.f : 0.f;
    }
    float rZ[4][4] = {}, rF[4][4] = {}, rW[4][4] = {};
    float cZ[4] = {}, cE[4] = {}, cW[4] = {};
    float aAll = 0.f, aC0 = 0.f, aR0 = 0.f, aRC = 0.f;
#pragma unroll
    for (int i = 0; i < 4; ++i)
#pragma unroll
        for (int r = 0; r < 4; ++r) {
            float mr = mrow[i][r];
            int yr = yrow[i][r];
#pragma unroll
            for (int j = 0; j < 4; ++j) {
                float S = acc[i][j][r];
                float L = s * S;
                float e1 = __expf(L);
                float e2 = __expf(S);
                float msk = (yr == ycol[j]) ? 1.f : 0.f;
                rZ[i][r] += e1; rF[i][r] += e1 * L; rW[i][r] += e1 * msk;
                cZ[j] += e2;    cE[j] += e2 * S;    cW[j] += e2 * msk;
                float tmp = S * mcol[j];
                aAll += S; aC0 += tmp; aR0 += S * mr; aRC += tmp * mr;
            }
        }
    // row partials: DPP all-reduce over the 16 lanes of each quad; guarded store
    const int p_row = bx * 2 + (cw >> 6);
#pragma unroll
    for (int i = 0; i < 4; ++i)
#pragma unroll
        for (int r = 0; r < 4; ++r) {
            rZ[i][r] = sum16(rZ[i][r]);
            rF[i][r] = sum16(rF[i][r]);
            rW[i][r] = sum16(rW[i][r]);
            if (l15 == (i * 4 + r)) {
                int grow = r0 + rw + i * 16 + quad * 4 + r;
                int base = ST_ROW + grow * 64 + p_row;
                st[base]          = rZ[i][r];
                st[base + 262144] = rF[i][r];
                st[base + 524288] = rW[i][r];
            }
        }
    // col partials: cross-quad steps stay as shfl (DPP16 can't cross rows)
    const int p_col = by * 2 + (rw >> 6);
#pragma unroll
    for (int j = 0; j < 4; ++j) {
        cZ[j] += __shfl_xor(cZ[j], 16); cZ[j] += __shfl_xor(cZ[j], 32);
        cE[j] += __shfl_xor(cE[j], 16); cE[j] += __shfl_xor(cE[j], 32);
        cW[j] += __shfl_xor(cW[j], 16); cW[j] += __shfl_xor(cW[j], 32);
        if (quad == 0) {
            int gcol = c0 + cw + j * 16 + l15;
            int base = ST_COL + gcol * 64 + p_col;
            st[base]          = cZ[j];
            st[base + 262144] = cE[j];
            st[base + 524288] = cW[j];
        }
    }
    // T scalars: intra-16 via DPP, cross-row via shfl
    aAll = sum16(aAll); aC0 = sum16(aC0); aR0 = sum16(aR0); aRC = sum16(aRC);
#pragma unroll
    for (int m = 16; m < 64; m <<= 1) {
        aAll += __shfl_xor(aAll, m); aC0 += __shfl_xor(aC0, m);
        aR0 += __shfl_xor(aR0, m);   aRC += __shfl_xor(aRC, m);
    }
    if (lane == 0) {
        int wg = (by * 32 + bx) * 4 + w;
        float T00 = aRC, T01 = aR0 - aRC, T10 = aC0 - aRC, T11 = aAll - aR0 - aC0 + aRC;
        st[ST_T + wg * 4 + 0] = T00;
        st[ST_T + wg * 4 + 1] = T01;
        st[ST_T + wg * 4 + 2] = T10;
        st[ST_T + wg * 4 + 3] = T11;
    }
}

// ---------------------------------------------------------------------------
// post: y<2 -> clip finalize (coalesced loads; lane=partial); y==2 -> gram.
// ---------------------------------------------------------------------------
__global__ __launch_bounds__(256) void post_kernel(const float* __restrict__ st1,
                                                   const float* __restrict__ st2,
                                                   const int* __restrict__ y,
                                                   float* __restrict__ RV,
                                                   float* __restrict__ TT,
                                                   const float* __restrict__ isp,
                                                   const float* __restrict__ ish,
                                                   const float* __restrict__ tsp,
                                                   const float* __restrict__ tsh,
                                                   float* __restrict__ GP) {
    __shared__ alignas(16) float sh[64 * 128];   // 32 KB union
    const int tid = threadIdx.x;
    if (blockIdx.y == 2) {
        if (blockIdx.x >= 256) return;
        float (*As2)[128] = (float(*)[128])sh;
        const int mat = blockIdx.x >> 6, chunk = blockIdx.x & 63;
        const float* A = mat == 0 ? isp : mat == 1 ? ish : mat == 2 ? tsp : tsh;
        const int m0 = chunk * 64;
#pragma unroll
        for (int r = 0; r < 8; ++r) {
            int idx = r * 256 + tid;
            int row = idx >> 5, c4 = (idx & 31) * 4;
            *(float4*)&As2[row][c4] = *(const float4*)&A[(size_t)(m0 + row) * 128 + c4];
        }
        __syncthreads();
        const int ty = tid >> 4, tx = tid & 15;
        float acc[8][8] = {};
        for (int k = 0; k < 64; ++k) {
            float av[8], bv[8];
            *(float4*)&av[0] = *(const float4*)&As2[k][ty * 8];
            *(float4*)&av[4] = *(const float4*)&As2[k][ty * 8 + 4];
            *(float4*)&bv[0] = *(const float4*)&As2[k][tx * 8];
            *(float4*)&bv[4] = *(const float4*)&As2[k][tx * 8 + 4];
#pragma unroll
            for (int i = 0; i < 8; ++i)
#pragma unroll
                for (int j = 0; j < 8; ++j) acc[i][j] += av[i] * bv[j];
        }
        float* Gp = GP + ((size_t)(mat * 64 + chunk) << 14);
#pragma unroll
        for (int i = 0; i < 8; ++i) {
            *(float4*)&Gp[(ty * 8 + i) * 128 + tx * 8]     = *(float4*)&acc[i][0];
            *(float4*)&Gp[(ty * 8 + i) * 128 + tx * 8 + 4] = *(float4*)&acc[i][4];
        }
        return;
    }
    float* cred = sh;                       // 256
    float4* tred = (float4*)(sh + 256);     // 256 float4
    const int z = blockIdx.y;
    const float* st = z ? st2 : st1;
    const int lane = tid & 63;
    const int k = blockIdx.x * 4 + (tid >> 6);
    const float Bf = (float)BSZ;

    float ccnt = 0.f;
    for (int i = tid; i < BSZ; i += 256) ccnt += (y[i] == 0) ? 1.f : 0.f;
    cred[tid] = ccnt;
    __syncthreads();
    for (int ss2 = 128; ss2 > 0; ss2 >>= 1) {
        if (tid < ss2) cred[tid] += cred[tid + ss2];
        __syncthreads();
    }
    const float n0 = cred[0];

    const int base = k * 64 + lane;
    float Z1 = st[ST_ROW + base];
    float F1 = st[ST_ROW + 262144 + base];
    float W1 = st[ST_ROW + 524288 + base];
    float Z2 = st[ST_COL + base];
    float E2 = st[ST_COL + 262144 + base];
    float W2 = st[ST_COL + 524288 + base];
    Z1 = sum16(Z1); F1 = sum16(F1); W1 = sum16(W1);
    Z2 = sum16(Z2); E2 = sum16(E2); W2 = sum16(W2);
#pragma unroll
    for (int m = 16; m < 64; m <<= 1) {
        Z1 += __shfl_xor(Z1, m); F1 += __shfl_xor(F1, m); W1 += __shfl_xor(W1, m);
        Z2 += __shfl_xor(Z2, m); E2 += __shfl_xor(E2, m); W2 += __shfl_xor(W2, m);
    }
    if (lane == 0) {
        int yk = y[k];
        float n = (yk == 0) ? n0 : (Bf - n0);
        float a = 1.0f / n;
        float ea = expf(a);
        float denom = n * ea + (Bf - n);
        float q_s = ea / denom, q_d = 1.0f / denom;
        float ld = logf(denom);
        float lq_s = a - ld, lq_d = -ld;
        float Qlq = n * q_s * lq_s + (Bf - n) * q_d * lq_d;
        float term_r = Qlq + F1 / Z1 - lq_d - (lq_s - lq_d) * (W1 / Z1);
        float term_c = Qlq + E2 / Z2 - lq_d - (lq_s - lq_d) * (W2 / Z2);
        RV[(size_t)z * BSZ + k] = (term_r + term_c) / (4.0f * Bf);
    }
    if (blockIdx.x == 0) {
        const float4* tp = (const float4*)&st[ST_T];
        float4 acc = {0.f, 0.f, 0.f, 0.f};
        for (int u = tid; u < 4096; u += 256) {
            float4 t4 = tp[u];
            acc.x += t4.x; acc.y += t4.y; acc.z += t4.z; acc.w += t4.w;
        }
        tred[tid] = acc;
        __syncthreads();
        for (int ss2 = 128; ss2 > 0; ss2 >>= 1) {
            if (tid < ss2) {
                tred[tid].x += tred[tid + ss2].x; tred[tid].y += tred[tid + ss2].y;
                tred[tid].z += tred[tid + ss2].z; tred[tid].w += tred[tid + ss2].w;
            }
            __syncthreads();
        }
        if (tid == 0) {
            TT[z * 4 + 0] = tred[0].x; TT[z * 4 + 1] = tred[0].y;
            TT[z * 4 + 2] = tred[0].z; TT[z * 4 + 3] = tred[0].w;
        }
    }
}

// frob_combine: grid (64,2), block 64 (1 wave). Each block: 256 entries.
__global__ void frob_combine(const float* __restrict__ GP, float* __restrict__ scal) {
    const int z = blockIdx.y;
    const int tid = threadIdx.x;
    int u = blockIdx.x * 256 + tid * 4;
    float4 ga = {0.f, 0.f, 0.f, 0.f};
    float4 gb = {0.f, 0.f, 0.f, 0.f};
    const size_t baseA = ((size_t)(2 * z) * 64) << 14;
    const size_t baseB = ((size_t)(2 * z + 1) * 64) << 14;
    for (int c = 0; c < 64; ++c) {
        float4 va = *(const float4*)&GP[baseA + ((size_t)c << 14) + u];
        float4 vb = *(const float4*)&GP[baseB + ((size_t)c << 14) + u];
        ga.x += va.x; ga.y += va.y; ga.z += va.z; ga.w += va.w;
        gb.x += vb.x; gb.y += vb.y; gb.z += vb.z; gb.w += vb.w;
    }
    float r = ga.x * gb.x + ga.y * gb.y + ga.z * gb.z + ga.w * gb.w;
    r = sum16(r);
#pragma unroll
    for (int m = 16; m < 64; m <<= 1) r += __shfl_xor(r, m);
    if (tid == 0) atomicAdd(&scal[3 + z], r);
}

// ---------------------------------------------------------------------------
// Final: sum RV per z (+ recount n0) + T tails + gram terms -> out[0]
// ---------------------------------------------------------------------------
__global__ void final_kernel(const float* __restrict__ RV, const float* __restrict__ scal,
                             const int* __restrict__ y,
                             const float* __restrict__ sl1, const float* __restrict__ sl2,
                             float* __restrict__ out) {
    __shared__ float red0[256], red1[256], red2[256];
    int tid = threadIdx.x;
    float s0 = 0.f, s1 = 0.f, cnt = 0.f;
    for (int u = tid; u < BSZ; u += 256) {
        s0 += RV[u]; s1 += RV[BSZ + u];
        cnt += (y[u] == 0) ? 1.f : 0.f;
    }
    red0[tid] = s0; red1[tid] = s1; red2[tid] = cnt;
    __syncthreads();
    for (int ss = 128; ss > 0; ss >>= 1) {
        if (tid < ss) {
            red0[tid] += red0[tid + ss]; red1[tid] += red1[tid + ss];
            red2[tid] += red2[tid + ss];
        }
        __syncthreads();
    }
    if (tid == 0) {
        const float Bf = (float)BSZ;
        float n0 = red2[0], n1 = Bf - n0;
        float e0 = expf(1.f / n0), e1 = expf(1.f / n1);
        float d0 = n0 * e0 + (Bf - n0), d1 = n1 * e1 + (Bf - n1);
        float qs0 = e0 / d0, qd0 = 1.f / d0, qs1 = e1 / d1, qd1 = 1.f / d1;
        float loss_z[2];
        for (int z = 0; z < 2; ++z) {
            float T00 = scal[8 + z * 4 + 0], T01 = scal[8 + z * 4 + 1];
            float T10 = scal[8 + z * 4 + 2], T11 = scal[8 + z * 4 + 3];
            float QS1 = qd0 * (T00 + T01) + (qs0 - qd0) * T00 + qd1 * (T10 + T11) + (qs1 - qd1) * T11;
            float QS2 = qd0 * (T00 + T10) + (qs0 - qd0) * T00 + qd1 * (T01 + T11) + (qs1 - qd1) * T11;
            float s = expf(z ? sl2[0] : sl1[0]);
            loss_z[z] = (z ? red1[0] : red0[0]) + (-s * QS1 - QS2) / (4.0f * Bf);
        }
        float loss_sp = 0.5f * (sqrtf(scal[4]) + sqrtf(scal[3]));
        out[0] = (loss_sp + loss_z[1] + loss_z[0]) / 3.0f;
    }
}

// ---------------------------------------------------------------------------
extern "C" void kernel_launch(void* const* d_in, const int* in_sizes, int n_in,
                              void* d_out, int out_size, void* d_ws, size_t ws_size,
                              hipStream_t stream) {
    const float* i_in  = (const float*)d_in[0];
    const float* t_in  = (const float*)d_in[1];
    const int*   y     = (const int*)d_in[2];
    const float* l1_w  = (const float*)d_in[3];
    const float* l1_b  = (const float*)d_in[4];
    const float* l2_w  = (const float*)d_in[5];
    const float* l2_b  = (const float*)d_in[6];
    const float* l3_w  = (const float*)d_in[7];
    const float* l3_b  = (const float*)d_in[8];
    const float* tl1_w = (const float*)d_in[9];
    const float* tl1_b = (const float*)d_in[10];
    const float* tl2_w = (const float*)d_in[11];
    const float* tl2_b = (const float*)d_in[12];
    const float* isp_w = (const float*)d_in[13];
    const float* isp_b = (const float*)d_in[14];
    const float* ish_w = (const float*)d_in[15];
    const float* ish_b = (const float*)d_in[16];
    const float* tsh_w = (const float*)d_in[17];
    const float* tsh_b = (const float*)d_in[18];
    const float* tsp_w = (const float*)d_in[19];
    const float* tsp_b = (const float*)d_in[20];
    const float* c1_w  = (const float*)d_in[21];
    const float* c1_b  = (const float*)d_in[22];
    const float* c2_w  = (const float*)d_in[23];
    const float* c2_b  = (const float*)d_in[24];
    const float* c3_w  = (const float*)d_in[25];
    const float* c3_b  = (const float*)d_in[26];
    const float* c4_w  = (const float*)d_in[27];
    const float* c4_b  = (const float*)d_in[28];
    const float* scale1 = (const float*)d_in[29];
    const float* scale2 = (const float*)d_in[30];

    float* ws = (float*)d_ws;
    float* SCAL = ws;                       // 64 (zeroed; [3],[4] frob; [8..15] T)
    float* RV   = ws + 64;                  // 2*4096
    float* ISP  = RV + 2 * BSZ;
    float* ISH  = ISP + (size_t)BSZ * 128;
    float* TSP  = ISH + (size_t)BSZ * 128;
    float* TSH  = TSP + (size_t)BSZ * 128;
    unsigned short* IB   = (unsigned short*)(TSH + (size_t)BSZ * 128);
    unsigned short* WB   = IB + (size_t)BSZ * 2048;      // 1294336
    unsigned short* FI1B = WB + 1294336;
    unsigned short* FI2B = FI1B + (size_t)BSZ * 512;
    unsigned short* FIB  = FI2B + (size_t)BSZ * 256;
    unsigned short* FT1B = FIB + (size_t)BSZ * 128;
    unsigned short* FTB  = FT1B + (size_t)BSZ * 128;
    unsigned short* FINB = FTB + (size_t)BSZ * 128;
    unsigned short* FTNB = FINB + (size_t)BSZ * 128;
    unsigned short* ISHN = FTNB + (size_t)BSZ * 128;
    unsigned short* TSHN = ISHN + (size_t)BSZ * 128;
    float* ST1 = (float*)IB;
    float* ST2 = ST1 + ST_FLOATS;
    float* GP  = ST2 + ST_FLOATS;

    float* out = (float*)d_out;

    hipMemsetAsync(d_ws, 0, 64 * sizeof(float), stream);
    prep_kernel<<<9584, 256, 0, stream>>>(i_in, l1_w, l2_w, l3_w, tl2_w, isp_w, ish_w, tsh_w, tsp_w,
                                          IB, t_in, tl1_w, tl1_b, FT1B);
    mfma_gemm64<<<dim3(4, 64), 256, 0, stream>>>(IB, WB, l1_b, FI1B, 512, 2048, 1);
    mfma_gemm64<<<dim3(2, 64), 256, 0, stream>>>(FI1B, WB + 1048576, l2_b, FI2B, 256, 512, 1);
    gemm34n<<<dim3(1, 32, 2), 256, 0, stream>>>(FI2B, FT1B, WB, l3_b, tl2_b, FIB, FTB, FINB, FTNB);
    heads4f<<<dim3(1, 32, 4), 256, 0, stream>>>(FIB, FTB, WB, isp_b, ish_b, tsh_b, tsp_b,
                                                c1_w, c2_w, c3_w, c4_w, c1_b, c2_b, c3_b, c4_b,
                                                ISP, ISH, TSH, TSP, ISHN, TSHN, out);
    clip_mfma<<<dim3(32, 32, 2), 256, 0, stream>>>(FINB, FTNB, ISHN, TSHN, y, scale1, scale2, ST1, ST2);
    post_kernel<<<dim3(1024, 3), 256, 0, stream>>>(ST1, ST2, y, RV, &SCAL[8], ISP, ISH, TSP, TSH, GP);
    frob_combine<<<dim3(64, 2), 64, 0, stream>>>(GP, SCAL);
    final_kernel<<<1, 256, 0, stream>>>(RV, SCAL, y, scale1, scale2, out);
}

// Round 12
// 281.843 us; speedup vs baseline: 1.7500x; 1.0286x over previous
//
#include <hip/hip_runtime.h>
#include <math.h>

#define BSZ 4096

typedef __attribute__((ext_vector_type(8))) short bf16x8;
typedef __attribute__((ext_vector_type(4))) float f32x4;

// ST layout (floats), TRANSPOSED for coalesced finalize loads:
//   rowZ@0, rowF@262144, rowW@524288   each [4096 row][64 part]
//   colZ@786432, colE@1048576, colW@1310720  each [4096 col][64 part]
//   Tpart@1572864 ([4096 waves][4])
#define ST_ROW 0
#define ST_COL 786432
#define ST_T   1572864
#define ST_FLOATS 1589248

__device__ __forceinline__ unsigned short f2b(float f) {
    unsigned u = __float_as_uint(f);
    u = u + 0x7fffu + ((u >> 16) & 1u);
    return (unsigned short)(u >> 16);
}
__device__ __forceinline__ float b2f(unsigned short s) {
    return __uint_as_float(((unsigned)s) << 16);
}

// DPP add: x += lane-permuted x (pure VALU, no DS pipe).
template <int CTRL>
__device__ __forceinline__ float dpp_add(float x) {
    int p = __builtin_amdgcn_update_dpp(0, __float_as_int(x), CTRL, 0xF, 0xF, true);
    return x + __int_as_float(p);
}
// All-reduce sum across each 16-lane row (all lanes get the total).
__device__ __forceinline__ float sum16(float x) {
    x = dpp_add<0xB1>(x);
    x = dpp_add<0x4E>(x);
    x = dpp_add<0x124>(x);
    x = dpp_add<0x128>(x);
    return x;
}

// ---------------------------------------------------------------------------
// prep: blocks <9456 cast i+weights -> bf16 IB|WB; blocks >=9456 run the
// tl1 SIMT GEMM (K=49, fp32 in, bf16 out). Independent work, one launch.
// ---------------------------------------------------------------------------
__global__ void prep_kernel(const float* __restrict__ i_in,
                            const float* __restrict__ l1, const float* __restrict__ l2,
                            const float* __restrict__ l3, const float* __restrict__ tl2,
                            const float* __restrict__ isp, const float* __restrict__ ish,
                            const float* __restrict__ tsh, const float* __restrict__ tsp,
                            unsigned short* __restrict__ o,
                            const float* __restrict__ t_in, const float* __restrict__ tl1_w,
                            const float* __restrict__ tl1_b, unsigned short* __restrict__ FT1B) {
    __shared__ float As[16][65];
    __shared__ float Ws[16][65];
    if (blockIdx.x < 9456) {
        int i = (blockIdx.x * 256 + threadIdx.x) * 4;
        if (i >= 9682944) return;
        const float* src; int off;
        if (i < 8388608)      { src = i_in; off = 0; }
        else if (i < 9437184) { src = l1;  off = 8388608; }
        else if (i < 9568256) { src = l2;  off = 9437184; }
        else if (i < 9601024) { src = l3;  off = 9568256; }
        else if (i < 9617408) { src = tl2; off = 9601024; }
        else if (i < 9633792) { src = isp; off = 9617408; }
        else if (i < 9650176) { src = ish; off = 9633792; }
        else if (i < 9666560) { src = tsh; off = 9650176; }
        else                  { src = tsp; off = 9666560; }
        float4 v = *(const float4*)(src + (i - off));
        ushort4 r;
        r.x = f2b(v.x); r.y = f2b(v.y); r.z = f2b(v.z); r.w = f2b(v.w);
        *(ushort4*)(o + i) = r;
        return;
    }
    const int b = blockIdx.x - 9456;
    const int tid = threadIdx.x;
    const int tx = tid & 15, ty = tid >> 4;
    const int m0 = (b >> 1) * 64, n0 = (b & 1) * 64;
    const int K = 49, N = 128;
    float acc[4][4] = {};
    const int lrow = tid >> 2;
    const int lkb = (tid & 3) * 4;
    for (int k0 = 0; k0 < K; k0 += 16) {
#pragma unroll
        for (int u = 0; u < 4; ++u) {
            int k = k0 + lkb + u;
            As[lkb + u][lrow] = (k < K) ? t_in[(size_t)(m0 + lrow) * K + k] : 0.0f;
            Ws[lkb + u][lrow] = (k < K) ? tl1_w[(size_t)(n0 + lrow) * K + k] : 0.0f;
        }
        __syncthreads();
#pragma unroll
        for (int kk = 0; kk < 16; ++kk) {
            float av[4], bv[4];
#pragma unroll
            for (int i = 0; i < 4; ++i) av[i] = As[kk][ty * 4 + i];
#pragma unroll
            for (int j = 0; j < 4; ++j) bv[j] = Ws[kk][tx * 4 + j];
#pragma unroll
            for (int i = 0; i < 4; ++i)
#pragma unroll
                for (int j = 0; j < 4; ++j) acc[i][j] += av[i] * bv[j];
        }
        __syncthreads();
    }
#pragma unroll
    for (int i = 0; i < 4; ++i)
#pragma unroll
        for (int j = 0; j < 4; ++j) {
            int n = n0 + tx * 4 + j;
            float v = fmaxf(acc[i][j] + tl1_b[n], 0.0f);
            FT1B[(size_t)(m0 + ty * 4 + i) * N + n] = f2b(v);
        }
}

// ---------------------------------------------------------------------------
// Shared MFMA tile loop (128-row tiles): acc = A @ W^T, 4 waves, BK=64.
// ---------------------------------------------------------------------------
__device__ __forceinline__ void mfma_loop(const unsigned short* __restrict__ A,
                                          const unsigned short* __restrict__ W,
                                          int K, int m0, int n0,
                                          short* As, short* Bs, f32x4 (&acc)[4][4]) {
    const int tid = threadIdx.x;
    const int w = tid >> 6, lane = tid & 63, quad = lane >> 4, l15 = lane & 15;
    const int rw = (w >> 1) * 64, cw = (w & 1) * 64;
    for (int k0 = 0; k0 < K; k0 += 64) {
#pragma unroll
        for (int r = 0; r < 4; ++r) {
            int idx = r * 256 + tid;
            int row = idx >> 3, cbp = idx & 7;
            int col = ((cbp ^ (row & 7)) << 3);
            *(bf16x8*)&As[row * 64 + cbp * 8] = *(const bf16x8*)&A[(size_t)(m0 + row) * K + k0 + col];
            *(bf16x8*)&Bs[row * 64 + cbp * 8] = *(const bf16x8*)&W[(size_t)(n0 + row) * K + k0 + col];
        }
        __syncthreads();
#pragma unroll
        for (int kb = 0; kb < 2; ++kb) {
            bf16x8 af[4], bfr[4];
            int cb = kb * 4 + quad;
#pragma unroll
            for (int i = 0; i < 4; ++i) {
                int row = rw + i * 16 + l15;
                af[i] = *(const bf16x8*)&As[row * 64 + ((cb ^ (row & 7)) << 3)];
            }
#pragma unroll
            for (int j = 0; j < 4; ++j) {
                int row = cw + j * 16 + l15;
                bfr[j] = *(const bf16x8*)&Bs[row * 64 + ((cb ^ (row & 7)) << 3)];
            }
#pragma unroll
            for (int i = 0; i < 4; ++i)
#pragma unroll
                for (int j = 0; j < 4; ++j)
                    acc[i][j] = __builtin_amdgcn_mfma_f32_16x16x32_bf16(af[i], bfr[j], acc[i][j], 0, 0, 0);
        }
        __syncthreads();
    }
}

// ---------------------------------------------------------------------------
// 64x128 M-tile MFMA GEMM (L1/L2): doubles grid occupancy vs 128-tile.
// ---------------------------------------------------------------------------
__global__ __launch_bounds__(256) void mfma_gemm64(const unsigned short* __restrict__ A,
                                                   const unsigned short* __restrict__ W,
                                                   const float* __restrict__ bias,
                                                   unsigned short* __restrict__ Cb,
                                                   int N, int K, int relu) {
    __shared__ alignas(16) short As[64 * 64];
    __shared__ alignas(16) short Bs[128 * 64];
    const int tid = threadIdx.x;
    const int w = tid >> 6, lane = tid & 63, quad = lane >> 4, l15 = lane & 15;
    const int rw = (w >> 1) * 32, cw = (w & 1) * 64;
    const int m0 = blockIdx.y * 64, n0 = blockIdx.x * 128;
    f32x4 acc[2][4];
#pragma unroll
    for (int i = 0; i < 2; ++i)
#pragma unroll
        for (int j = 0; j < 4; ++j) acc[i][j] = (f32x4){0.f, 0.f, 0.f, 0.f};
    for (int k0 = 0; k0 < K; k0 += 64) {
#pragma unroll
        for (int r = 0; r < 2; ++r) {
            int idx = r * 256 + tid;
            int row = idx >> 3, cbp = idx & 7;
            int col = ((cbp ^ (row & 7)) << 3);
            *(bf16x8*)&As[row * 64 + cbp * 8] = *(const bf16x8*)&A[(size_t)(m0 + row) * K + k0 + col];
        }
#pragma unroll
        for (int r = 0; r < 4; ++r) {
            int idx = r * 256 + tid;
            int row = idx >> 3, cbp = idx & 7;
            int col = ((cbp ^ (row & 7)) << 3);
            *(bf16x8*)&Bs[row * 64 + cbp * 8] = *(const bf16x8*)&W[(size_t)(n0 + row) * K + k0 + col];
        }
        __syncthreads();
#pragma unroll
        for (int kb = 0; kb < 2; ++kb) {
            bf16x8 af[2], bfr[4];
            int cb = kb * 4 + quad;
#pragma unroll
            for (int i = 0; i < 2; ++i) {
                int row = rw + i * 16 + l15;
                af[i] = *(const bf16x8*)&As[row * 64 + ((cb ^ (row & 7)) << 3)];
            }
#pragma unroll
            for (int j = 0; j < 4; ++j) {
                int row = cw + j * 16 + l15;
                bfr[j] = *(const bf16x8*)&Bs[row * 64 + ((cb ^ (row & 7)) << 3)];
            }
#pragma unroll
            for (int i = 0; i < 2; ++i)
#pragma unroll
                for (int j = 0; j < 4; ++j)
                    acc[i][j] = __builtin_amdgcn_mfma_f32_16x16x32_bf16(af[i], bfr[j], acc[i][j], 0, 0, 0);
        }
        __syncthreads();
    }
#pragma unroll
    for (int j = 0; j < 4; ++j) {
        int n = n0 + cw + j * 16 + l15;
        float bv = bias[n];
#pragma unroll
        for (int i = 0; i < 2; ++i)
#pragma unroll
            for (int r = 0; r < 4; ++r) {
                int m = m0 + rw + i * 16 + quad * 4 + r;
                float v = acc[i][j][r] + bv;
                if (relu) v = fmaxf(v, 0.f);
                Cb[(size_t)m * N + n] = f2b(v);
            }
    }
}

// ---------------------------------------------------------------------------
// Chain tails + FUSED row-normalize. z=0: FI2B@l3 (K=256) -> FIB,FINB;
// z=1: FT1B@tl2 (K=128) -> FTB,FTNB. N=128.
// ---------------------------------------------------------------------------
__global__ __launch_bounds__(256) void gemm34n(const unsigned short* __restrict__ FI2B,
                                               const unsigned short* __restrict__ FT1B,
                                               const unsigned short* __restrict__ WB,
                                               const float* __restrict__ l3_b,
                                               const float* __restrict__ tl2_b,
                                               unsigned short* __restrict__ FIB,
                                               unsigned short* __restrict__ FTB,
                                               unsigned short* __restrict__ FINB,
                                               unsigned short* __restrict__ FTNB) {
    __shared__ alignas(16) short As[128 * 64];
    __shared__ alignas(16) short Bs[128 * 64];
    __shared__ float rowss[128];
    const int tid = threadIdx.x;
    if (tid < 128) rowss[tid] = 0.f;
    const int z = blockIdx.z;
    const unsigned short* A = z ? FT1B : FI2B;
    const unsigned short* W = z ? (WB + 1212416) : (WB + 1179648);
    const float* bias = z ? tl2_b : l3_b;
    unsigned short* Cb = z ? FTB : FIB;
    unsigned short* CN = z ? FTNB : FINB;
    const int K = z ? 128 : 256;
    const int w = tid >> 6, lane = tid & 63, quad = lane >> 4, l15 = lane & 15;
    const int rw = (w >> 1) * 64, cw = (w & 1) * 64;
    const int m0 = blockIdx.y * 128;
    f32x4 acc[4][4];
#pragma unroll
    for (int i = 0; i < 4; ++i)
#pragma unroll
        for (int j = 0; j < 4; ++j) acc[i][j] = (f32x4){0.f, 0.f, 0.f, 0.f};
    mfma_loop(A, W, K, m0, 0, As, Bs, acc);
    float bv[4];
#pragma unroll
    for (int j = 0; j < 4; ++j) bv[j] = bias[cw + j * 16 + l15];
#pragma unroll
    for (int i = 0; i < 4; ++i)
#pragma unroll
        for (int r = 0; r < 4; ++r) {
            float ssp = 0.f;
#pragma unroll
            for (int j = 0; j < 4; ++j) {
                float v = acc[i][j][r] + bv[j];
                ssp += v * v;
            }
            ssp = sum16(ssp);
            if (l15 == 0) atomicAdd(&rowss[rw + i * 16 + quad * 4 + r], ssp);
        }
    __syncthreads();
#pragma unroll
    for (int i = 0; i < 4; ++i)
#pragma unroll
        for (int r = 0; r < 4; ++r) {
            int lrow = rw + i * 16 + quad * 4 + r;
            float inv = 1.f / fmaxf(sqrtf(rowss[lrow]), 1e-12f);
#pragma unroll
            for (int j = 0; j < 4; ++j) {
                int n = cw + j * 16 + l15;
                float v = acc[i][j][r] + bv[j];
                Cb[(size_t)(m0 + lrow) * 128 + n] = f2b(v);
                CN[(size_t)(m0 + lrow) * 128 + n] = f2b(v * inv);
            }
        }
}

// ---------------------------------------------------------------------------
// SS heads + FUSED rownorm (z=1,2) + FUSED scalar head dot.
// ---------------------------------------------------------------------------
__global__ __launch_bounds__(256) void heads4f(const unsigned short* __restrict__ FIB,
                                               const unsigned short* __restrict__ FTB,
                                               const unsigned short* __restrict__ WB,
                                               const float* __restrict__ bisp, const float* __restrict__ bish,
                                               const float* __restrict__ btsh, const float* __restrict__ btsp,
                                               const float* __restrict__ c1w, const float* __restrict__ c2w,
                                               const float* __restrict__ c3w, const float* __restrict__ c4w,
                                               const float* __restrict__ c1b, const float* __restrict__ c2b,
                                               const float* __restrict__ c3b, const float* __restrict__ c4b,
                                               float* __restrict__ ISP, float* __restrict__ ISH,
                                               float* __restrict__ TSH, float* __restrict__ TSP,
                                               unsigned short* __restrict__ ISHN,
                                               unsigned short* __restrict__ TSHN,
                                               float* __restrict__ out) {
    __shared__ alignas(16) short As[128 * 64];
    __shared__ alignas(16) short Bs[128 * 64];
    __shared__ float rowss[128];
    __shared__ float rowdot[128];
    const int tid = threadIdx.x;
    if (tid < 128) { rowss[tid] = 0.f; rowdot[tid] = 0.f; }
    const int z = blockIdx.z;
    const unsigned short* A = (z < 2) ? FIB : FTB;
    const unsigned short* W = WB + (z == 0 ? 1228800 : z == 1 ? 1245184 : z == 2 ? 1261568 : 1277952);
    const float* bias = z == 0 ? bisp : z == 1 ? bish : z == 2 ? btsh : btsp;
    const float* hw = z == 0 ? c1w : z == 1 ? c2w : z == 2 ? c3w : c4w;
    const float* hb = z == 0 ? c1b : z == 1 ? c2b : z == 2 ? c3b : c4b;
    float* Cf = z == 0 ? ISP : z == 1 ? ISH : z == 2 ? TSH : TSP;
    unsigned short* CN = z == 1 ? ISHN : z == 2 ? TSHN : nullptr;
    const int outoff = z == 0 ? 0 : z == 1 ? 1 : z == 2 ? 3 : 2;
    const int do_norm = (z == 1 || z == 2);
    const int w = tid >> 6, lane = tid & 63, quad = lane >> 4, l15 = lane & 15;
    const int rw = (w >> 1) * 64, cw = (w & 1) * 64;
    const int m0 = blockIdx.y * 128;
    f32x4 acc[4][4];
#pragma unroll
    for (int i = 0; i < 4; ++i)
#pragma unroll
        for (int j = 0; j < 4; ++j) acc[i][j] = (f32x4){0.f, 0.f, 0.f, 0.f};
    mfma_loop(A, W, 128, m0, 0, As, Bs, acc);
    float bv[4], wv[4];
#pragma unroll
    for (int j = 0; j < 4; ++j) {
        int n = cw + j * 16 + l15;
        bv[j] = bias[n];
        wv[j] = hw[n];
    }
#pragma unroll
    for (int i = 0; i < 4; ++i)
#pragma unroll
        for (int r = 0; r < 4; ++r) {
            float ssp = 0.f, dp = 0.f;
#pragma unroll
            for (int j = 0; j < 4; ++j) {
                float v = acc[i][j][r] + bv[j];
                ssp += v * v;
                dp += v * wv[j];
            }
            ssp = sum16(ssp);
            dp = sum16(dp);
            if (l15 == 0) {
                int lrow = rw + i * 16 + quad * 4 + r;
                atomicAdd(&rowdot[lrow], dp);
                if (do_norm) atomicAdd(&rowss[lrow], ssp);
            }
        }
    __syncthreads();
#pragma unroll
    for (int i = 0; i < 4; ++i)
#pragma unroll
        for (int r = 0; r < 4; ++r) {
            int lrow = rw + i * 16 + quad * 4 + r;
            float inv = do_norm ? (1.f / fmaxf(sqrtf(rowss[lrow]), 1e-12f)) : 0.f;
#pragma unroll
            for (int j = 0; j < 4; ++j) {
                int n = cw + j * 16 + l15;
                float v = acc[i][j][r] + bv[j];
                Cf[(size_t)(m0 + lrow) * 128 + n] = v;
                if (do_norm) CN[(size_t)(m0 + lrow) * 128 + n] = f2b(v * inv);
            }
        }
    if (tid < 128) out[1 + (size_t)outoff * BSZ + m0 + tid] = rowdot[tid] + hb[0];
}

// ---------------------------------------------------------------------------
// MFMA CLIP tile (z=2 merged): R11 structure + algebraically-reduced stats:
//  - label masks via mcol/mrow fma accumulation (no v_cmp/cndmask); final
//    rW/cW selected once at store: rW = yr==0 ? rW0 : rZ-rW0 (y is binary)
//  - T scalars from per-column partials colS/colSR (2 ops/elem vs 5)
//  - rF = s * sum(e1*S), s factored out of the loop
// DO NOT: transpose-reduce (R6 VGPR blowup) / LDS same-addr atomics (R8).
// ---------------------------------------------------------------------------
__global__ __launch_bounds__(256) void clip_mfma(const unsigned short* __restrict__ In1,
                                                 const unsigned short* __restrict__ Tn1,
                                                 const unsigned short* __restrict__ In2,
                                                 const unsigned short* __restrict__ Tn2,
                                                 const int* __restrict__ y,
                                                 const float* __restrict__ scale_log1,
                                                 const float* __restrict__ scale_log2,
                                                 float* __restrict__ st1, float* __restrict__ st2) {
    __shared__ alignas(16) short As[128 * 64];
    __shared__ alignas(16) short Bs[128 * 64];
    const int z = blockIdx.z;
    const unsigned short* In = z ? In2 : In1;
    const unsigned short* Tn = z ? Tn2 : Tn1;
    const float* scale_log = z ? scale_log2 : scale_log1;
    float* st = z ? st2 : st1;
    const int tid = threadIdx.x;
    const int w = tid >> 6, lane = tid & 63, quad = lane >> 4, l15 = lane & 15;
    const int bx = blockIdx.x, by = blockIdx.y;
    const int r0 = by * 128, c0 = bx * 128;
    const int rw = (w >> 1) * 64, cw = (w & 1) * 64;
    f32x4 acc[4][4];
#pragma unroll
    for (int i = 0; i < 4; ++i)
#pragma unroll
        for (int j = 0; j < 4; ++j) acc[i][j] = (f32x4){0.f, 0.f, 0.f, 0.f};
    mfma_loop(In, Tn, 128, r0, c0, As, Bs, acc);

    const float s = expf(scale_log[0]);
    float mrow[4][4];
    float mcol[4];
#pragma unroll
    for (int i = 0; i < 4; ++i)
#pragma unroll
        for (int r = 0; r < 4; ++r)
            mrow[i][r] = (y[r0 + rw + i * 16 + quad * 4 + r] == 0) ? 1.f : 0.f;
#pragma unroll
    for (int j = 0; j < 4; ++j)
        mcol[j] = (y[c0 + cw + j * 16 + l15] == 0) ? 1.f : 0.f;

    float rZ[4][4] = {}, rFS[4][4] = {}, rW0[4][4] = {};
    float cZ[4] = {}, cE[4] = {}, cW0[4] = {};
    float colS[4] = {}, colSR[4] = {};
#pragma unroll
    for (int i = 0; i < 4; ++i)
#pragma unroll
        for (int r = 0; r < 4; ++r) {
            const float mr = mrow[i][r];
#pragma unroll
            for (int j = 0; j < 4; ++j) {
                float S = acc[i][j][r];
                float e1 = __expf(s * S);
                float e2 = __expf(S);
                rZ[i][r] += e1; rFS[i][r] += e1 * S; rW0[i][r] += e1 * mcol[j];
                cZ[j] += e2;    cE[j] += e2 * S;     cW0[j] += e2 * mr;
                colS[j] += S;   colSR[j] += S * mr;
            }
        }
    // row partials: DPP all-reduce; store with deferred rW selection
    const int p_row = bx * 2 + (cw >> 6);
#pragma unroll
    for (int i = 0; i < 4; ++i)
#pragma unroll
        for (int r = 0; r < 4; ++r) {
            rZ[i][r] = sum16(rZ[i][r]);
            rFS[i][r] = sum16(rFS[i][r]);
            rW0[i][r] = sum16(rW0[i][r]);
            if (l15 == (i * 4 + r)) {
                float mr = mrow[i][r];
                float rw_f = mr * rW0[i][r] + (1.f - mr) * (rZ[i][r] - rW0[i][r]);
                int grow = r0 + rw + i * 16 + quad * 4 + r;
                int base = ST_ROW + grow * 64 + p_row;
                st[base]          = rZ[i][r];
                st[base + 262144] = s * rFS[i][r];
                st[base + 524288] = rw_f;
            }
        }
    // col partials: cross-quad shfl; store with deferred cW selection
    const int p_col = by * 2 + (rw >> 6);
#pragma unroll
    for (int j = 0; j < 4; ++j) {
        cZ[j] += __shfl_xor(cZ[j], 16); cZ[j] += __shfl_xor(cZ[j], 32);
        cE[j] += __shfl_xor(cE[j], 16); cE[j] += __shfl_xor(cE[j], 32);
        cW0[j] += __shfl_xor(cW0[j], 16); cW0[j] += __shfl_xor(cW0[j], 32);
        if (quad == 0) {
            float mc = mcol[j];
            float cw_f = mc * cW0[j] + (1.f - mc) * (cZ[j] - cW0[j]);
            int gcol = c0 + cw + j * 16 + l15;
            int base = ST_COL + gcol * 64 + p_col;
            st[base]          = cZ[j];
            st[base + 262144] = cE[j];
            st[base + 524288] = cw_f;
        }
    }
    // T scalars from per-column partials (16 ops/thread), then wave reduce
    float aAll = 0.f, aC0 = 0.f, aR0 = 0.f, aRC = 0.f;
#pragma unroll
    for (int j = 0; j < 4; ++j) {
        aAll += colS[j];
        aC0 += mcol[j] * colS[j];
        aR0 += colSR[j];
        aRC += mcol[j] * colSR[j];
    }
    aAll = sum16(aAll); aC0 = sum16(aC0); aR0 = sum16(aR0); aRC = sum16(aRC);
#pragma unroll
    for (int m = 16; m < 64; m <<= 1) {
        aAll += __shfl_xor(aAll, m); aC0 += __shfl_xor(aC0, m);
        aR0 += __shfl_xor(aR0, m);   aRC += __shfl_xor(aRC, m);
    }
    if (lane == 0) {
        int wg = (by * 32 + bx) * 4 + w;
        float T00 = aRC, T01 = aR0 - aRC, T10 = aC0 - aRC, T11 = aAll - aR0 - aC0 + aRC;
        st[ST_T + wg * 4 + 0] = T00;
        st[ST_T + wg * 4 + 1] = T01;
        st[ST_T + wg * 4 + 2] = T10;
        st[ST_T + wg * 4 + 3] = T11;
    }
}

// ---------------------------------------------------------------------------
// post: y<2 -> clip finalize (coalesced loads; lane=partial); y==2 -> gram.
// ---------------------------------------------------------------------------
__global__ __launch_bounds__(256) void post_kernel(const float* __restrict__ st1,
                                                   const float* __restrict__ st2,
                                                   const int* __restrict__ y,
                                                   float* __restrict__ RV,
                                                   float* __restrict__ TT,
                                                   const float* __restrict__ isp,
                                                   const float* __restrict__ ish,
                                                   const float* __restrict__ tsp,
                                                   const float* __restrict__ tsh,
                                                   float* __restrict__ GP) {
    __shared__ alignas(16) float sh[64 * 128];   // 32 KB union
    const int tid = threadIdx.x;
    if (blockIdx.y == 2) {
        if (blockIdx.x >= 256) return;
        float (*As2)[128] = (float(*)[128])sh;
        const int mat = blockIdx.x >> 6, chunk = blockIdx.x & 63;
        const float* A = mat == 0 ? isp : mat == 1 ? ish : mat == 2 ? tsp : tsh;
        const int m0 = chunk * 64;
#pragma unroll
        for (int r = 0; r < 8; ++r) {
            int idx = r * 256 + tid;
            int row = idx >> 5, c4 = (idx & 31) * 4;
            *(float4*)&As2[row][c4] = *(const float4*)&A[(size_t)(m0 + row) * 128 + c4];
        }
        __syncthreads();
        const int ty = tid >> 4, tx = tid & 15;
        float acc[8][8] = {};
        for (int k = 0; k < 64; ++k) {
            float av[8], bv[8];
            *(float4*)&av[0] = *(const float4*)&As2[k][ty * 8];
            *(float4*)&av[4] = *(const float4*)&As2[k][ty * 8 + 4];
            *(float4*)&bv[0] = *(const float4*)&As2[k][tx * 8];
            *(float4*)&bv[4] = *(const float4*)&As2[k][tx * 8 + 4];
#pragma unroll
            for (int i = 0; i < 8; ++i)
#pragma unroll
                for (int j = 0; j < 8; ++j) acc[i][j] += av[i] * bv[j];
        }
        float* Gp = GP + ((size_t)(mat * 64 + chunk) << 14);
#pragma unroll
        for (int i = 0; i < 8; ++i) {
            *(float4*)&Gp[(ty * 8 + i) * 128 + tx * 8]     = *(float4*)&acc[i][0];
            *(float4*)&Gp[(ty * 8 + i) * 128 + tx * 8 + 4] = *(float4*)&acc[i][4];
        }
        return;
    }
    float* cred = sh;                       // 256
    float4* tred = (float4*)(sh + 256);     // 256 float4
    const int z = blockIdx.y;
    const float* st = z ? st2 : st1;
    const int lane = tid & 63;
    const int k = blockIdx.x * 4 + (tid >> 6);
    const float Bf = (float)BSZ;

    float ccnt = 0.f;
    for (int i = tid; i < BSZ; i += 256) ccnt += (y[i] == 0) ? 1.f : 0.f;
    cred[tid] = ccnt;
    __syncthreads();
    for (int ss2 = 128; ss2 > 0; ss2 >>= 1) {
        if (tid < ss2) cred[tid] += cred[tid + ss2];
        __syncthreads();
    }
    const float n0 = cred[0];

    const int base = k * 64 + lane;
    float Z1 = st[ST_ROW + base];
    float F1 = st[ST_ROW + 262144 + base];
    float W1 = st[ST_ROW + 524288 + base];
    float Z2 = st[ST_COL + base];
    float E2 = st[ST_COL + 262144 + base];
    float W2 = st[ST_COL + 524288 + base];
    Z1 = sum16(Z1); F1 = sum16(F1); W1 = sum16(W1);
    Z2 = sum16(Z2); E2 = sum16(E2); W2 = sum16(W2);
#pragma unroll
    for (int m = 16; m < 64; m <<= 1) {
        Z1 += __shfl_xor(Z1, m); F1 += __shfl_xor(F1, m); W1 += __shfl_xor(W1, m);
        Z2 += __shfl_xor(Z2, m); E2 += __shfl_xor(E2, m); W2 += __shfl_xor(W2, m);
    }
    if (lane == 0) {
        int yk = y[k];
        float n = (yk == 0) ? n0 : (Bf - n0);
        float a = 1.0f / n;
        float ea = expf(a);
        float denom = n * ea + (Bf - n);
        float q_s = ea / denom, q_d = 1.0f / denom;
        float ld = logf(denom);
        float lq_s = a - ld, lq_d = -ld;
        float Qlq = n * q_s * lq_s + (Bf - n) * q_d * lq_d;
        float term_r = Qlq + F1 / Z1 - lq_d - (lq_s - lq_d) * (W1 / Z1);
        float term_c = Qlq + E2 / Z2 - lq_d - (lq_s - lq_d) * (W2 / Z2);
        RV[(size_t)z * BSZ + k] = (term_r + term_c) / (4.0f * Bf);
    }
    if (blockIdx.x == 0) {
        const float4* tp = (const float4*)&st[ST_T];
        float4 acc = {0.f, 0.f, 0.f, 0.f};
        for (int u = tid; u < 4096; u += 256) {
            float4 t4 = tp[u];
            acc.x += t4.x; acc.y += t4.y; acc.z += t4.z; acc.w += t4.w;
        }
        tred[tid] = acc;
        __syncthreads();
        for (int ss2 = 128; ss2 > 0; ss2 >>= 1) {
            if (tid < ss2) {
                tred[tid].x += tred[tid + ss2].x; tred[tid].y += tred[tid + ss2].y;
                tred[tid].z += tred[tid + ss2].z; tred[tid].w += tred[tid + ss2].w;
            }
            __syncthreads();
        }
        if (tid == 0) {
            TT[z * 4 + 0] = tred[0].x; TT[z * 4 + 1] = tred[0].y;
            TT[z * 4 + 2] = tred[0].z; TT[z * 4 + 3] = tred[0].w;
        }
    }
}

// frob_combine: grid (64,2), block 64 (1 wave). Each block: 256 entries.
__global__ void frob_combine(const float* __restrict__ GP, float* __restrict__ scal) {
    const int z = blockIdx.y;
    const int tid = threadIdx.x;
    int u = blockIdx.x * 256 + tid * 4;
    float4 ga = {0.f, 0.f, 0.f, 0.f};
    float4 gb = {0.f, 0.f, 0.f, 0.f};
    const size_t baseA = ((size_t)(2 * z) * 64) << 14;
    const size_t baseB = ((size_t)(2 * z + 1) * 64) << 14;
    for (int c = 0; c < 64; ++c) {
        float4 va = *(const float4*)&GP[baseA + ((size_t)c << 14) + u];
        float4 vb = *(const float4*)&GP[baseB + ((size_t)c << 14) + u];
        ga.x += va.x; ga.y += va.y; ga.z += va.z; ga.w += va.w;
        gb.x += vb.x; gb.y += vb.y; gb.z += vb.z; gb.w += vb.w;
    }
    float r = ga.x * gb.x + ga.y * gb.y + ga.z * gb.z + ga.w * gb.w;
    r = sum16(r);
#pragma unroll
    for (int m = 16; m < 64; m <<= 1) r += __shfl_xor(r, m);
    if (tid == 0) atomicAdd(&scal[3 + z], r);
}

// ---------------------------------------------------------------------------
// Final: sum RV per z (+ recount n0) + T tails + gram terms -> out[0]
// ---------------------------------------------------------------------------
__global__ void final_kernel(const float* __restrict__ RV, const float* __restrict__ scal,
                             const int* __restrict__ y,
                             const float* __restrict__ sl1, const float* __restrict__ sl2,
                             float* __restrict__ out) {
    __shared__ float red0[256], red1[256], red2[256];
    int tid = threadIdx.x;
    float s0 = 0.f, s1 = 0.f, cnt = 0.f;
    for (int u = tid; u < BSZ; u += 256) {
        s0 += RV[u]; s1 += RV[BSZ + u];
        cnt += (y[u] == 0) ? 1.f : 0.f;
    }
    red0[tid] = s0; red1[tid] = s1; red2[tid] = cnt;
    __syncthreads();
    for (int ss = 128; ss > 0; ss >>= 1) {
        if (tid < ss) {
            red0[tid] += red0[tid + ss]; red1[tid] += red1[tid + ss];
            red2[tid] += red2[tid + ss];
        }
        __syncthreads();
    }
    if (tid == 0) {
        const float Bf = (float)BSZ;
        float n0 = red2[0], n1 = Bf - n0;
        float e0 = expf(1.f / n0), e1 = expf(1.f / n1);
        float d0 = n0 * e0 + (Bf - n0), d1 = n1 * e1 + (Bf - n1);
        float qs0 = e0 / d0, qd0 = 1.f / d0, qs1 = e1 / d1, qd1 = 1.f / d1;
        float loss_z[2];
        for (int z = 0; z < 2; ++z) {
            float T00 = scal[8 + z * 4 + 0], T01 = scal[8 + z * 4 + 1];
            float T10 = scal[8 + z * 4 + 2], T11 = scal[8 + z * 4 + 3];
            float QS1 = qd0 * (T00 + T01) + (qs0 - qd0) * T00 + qd1 * (T10 + T11) + (qs1 - qd1) * T11;
            float QS2 = qd0 * (T00 + T10) + (qs0 - qd0) * T00 + qd1 * (T01 + T11) + (qs1 - qd1) * T11;
            float s = expf(z ? sl2[0] : sl1[0]);
            loss_z[z] = (z ? red1[0] : red0[0]) + (-s * QS1 - QS2) / (4.0f * Bf);
        }
        float loss_sp = 0.5f * (sqrtf(scal[4]) + sqrtf(scal[3]));
        out[0] = (loss_sp + loss_z[1] + loss_z[0]) / 3.0f;
    }
}

// ---------------------------------------------------------------------------
extern "C" void kernel_launch(void* const* d_in, const int* in_sizes, int n_in,
                              void* d_out, int out_size, void* d_ws, size_t ws_size,
                              hipStream_t stream) {
    const float* i_in  = (const float*)d_in[0];
    const float* t_in  = (const float*)d_in[1];
    const int*   y     = (const int*)d_in[2];
    const float* l1_w  = (const float*)d_in[3];
    const float* l1_b  = (const float*)d_in[4];
    const float* l2_w  = (const float*)d_in[5];
    const float* l2_b  = (const float*)d_in[6];
    const float* l3_w  = (const float*)d_in[7];
    const float* l3_b  = (const float*)d_in[8];
    const float* tl1_w = (const float*)d_in[9];
    const float* tl1_b = (const float*)d_in[10];
    const float* tl2_w = (const float*)d_in[11];
    const float* tl2_b = (const float*)d_in[12];
    const float* isp_w = (const float*)d_in[13];
    const float* isp_b = (const float*)d_in[14];
    const float* ish_w = (const float*)d_in[15];
    const float* ish_b = (const float*)d_in[16];
    const float* tsh_w = (const float*)d_in[17];
    const float* tsh_b = (const float*)d_in[18];
    const float* tsp_w = (const float*)d_in[19];
    const float* tsp_b = (const float*)d_in[20];
    const float* c1_w  = (const float*)d_in[21];
    const float* c1_b  = (const float*)d_in[22];
    const float* c2_w  = (const float*)d_in[23];
    const float* c2_b  = (const float*)d_in[24];
    const float* c3_w  = (const float*)d_in[25];
    const float* c3_b  = (const float*)d_in[26];
    const float* c4_w  = (const float*)d_in[27];
    const float* c4_b  = (const float*)d_in[28];
    const float* scale1 = (const float*)d_in[29];
    const float* scale2 = (const float*)d_in[30];

    float* ws = (float*)d_ws;
    float* SCAL = ws;                       // 64 (zeroed; [3],[4] frob; [8..15] T)
    float* RV   = ws + 64;                  // 2*4096
    float* ISP  = RV + 2 * BSZ;
    float* ISH  = ISP + (size_t)BSZ * 128;
    float* TSP  = ISH + (size_t)BSZ * 128;
    float* TSH  = TSP + (size_t)BSZ * 128;
    unsigned short* IB   = (unsigned short*)(TSH + (size_t)BSZ * 128);
    unsigned short* WB   = IB + (size_t)BSZ * 2048;      // 1294336
    unsigned short* FI1B = WB + 1294336;
    unsigned short* FI2B = FI1B + (size_t)BSZ * 512;
    unsigned short* FIB  = FI2B + (size_t)BSZ * 256;
    unsigned short* FT1B = FIB + (size_t)BSZ * 128;
    unsigned short* FTB  = FT1B + (size_t)BSZ * 128;
    unsigned short* FINB = FTB + (size_t)BSZ * 128;
    unsigned short* FTNB = FINB + (size_t)BSZ * 128;
    unsigned short* ISHN = FTNB + (size_t)BSZ * 128;
    unsigned short* TSHN = ISHN + (size_t)BSZ * 128;
    float* ST1 = (float*)IB;
    float* ST2 = ST1 + ST_FLOATS;
    float* GP  = ST2 + ST_FLOATS;

    float* out = (float*)d_out;

    hipMemsetAsync(d_ws, 0, 64 * sizeof(float), stream);
    prep_kernel<<<9584, 256, 0, stream>>>(i_in, l1_w, l2_w, l3_w, tl2_w, isp_w, ish_w, tsh_w, tsp_w,
                                          IB, t_in, tl1_w, tl1_b, FT1B);
    mfma_gemm64<<<dim3(4, 64), 256, 0, stream>>>(IB, WB, l1_b, FI1B, 512, 2048, 1);
    mfma_gemm64<<<dim3(2, 64), 256, 0, stream>>>(FI1B, WB + 1048576, l2_b, FI2B, 256, 512, 1);
    gemm34n<<<dim3(1, 32, 2), 256, 0, stream>>>(FI2B, FT1B, WB, l3_b, tl2_b, FIB, FTB, FINB, FTNB);
    heads4f<<<dim3(1, 32, 4), 256, 0, stream>>>(FIB, FTB, WB, isp_b, ish_b, tsh_b, tsp_b,
                                                c1_w, c2_w, c3_w, c4_w, c1_b, c2_b, c3_b, c4_b,
                                                ISP, ISH, TSH, TSP, ISHN, TSHN, out);
    clip_mfma<<<dim3(32, 32, 2), 256, 0, stream>>>(FINB, FTNB, ISHN, TSHN, y, scale1, scale2, ST1, ST2);
    post_kernel<<<dim3(1024, 3), 256, 0, stream>>>(ST1, ST2, y, RV, &SCAL[8], ISP, ISH, TSP, TSH, GP);
    frob_combine<<<dim3(64, 2), 64, 0, stream>>>(GP, SCAL);
    final_kernel<<<1, 256, 0, stream>>>(RV, SCAL, y, scale1, scale2, out);
}